// Round 7
// baseline (413.225 us; speedup 1.0000x reference)
//
#include <hip/hip_runtime.h>

// ---------- common helpers ----------
typedef short bf16x8 __attribute__((ext_vector_type(8)));
typedef float f32x4 __attribute__((ext_vector_type(4)));

__device__ __forceinline__ void async16(const void* g, const void* l) {
  __builtin_amdgcn_global_load_lds(
      (const __attribute__((address_space(1))) unsigned int*)g,
      (__attribute__((address_space(3))) unsigned int*)(void*)(uintptr_t)l,
      16, 0, 0);
}

__device__ __forceinline__ unsigned short f2b(float f) {
  unsigned int u = __float_as_uint(f);
  u += 0x7fffu + ((u >> 16) & 1u);   // round-to-nearest-even
  return (unsigned short)(u >> 16);
}

// ---------- cast fp32 -> bf16, n % 1024 == 0 ----------
__global__ __launch_bounds__(256) void cast_f32_bf16(
    const float* __restrict__ in, unsigned short* __restrict__ out, int n) {
  int i = (blockIdx.x * 256 + threadIdx.x) * 4;
  if (i < n) {
    float4 v = *(const float4*)(in + i);
    ushort4 o;
    o.x = f2b(v.x); o.y = f2b(v.y); o.z = f2b(v.z); o.w = f2b(v.w);
    *(ushort4*)(out + i) = o;
  }
}

// ---------- transpose+cast: out_bf16[N][K] = in_f32[K][N], K,N multiples of 64 ----------
__global__ __launch_bounds__(256) void transpose_cast(
    const float* __restrict__ in, unsigned short* __restrict__ out,
    int K, int N) {
  __shared__ __align__(16) unsigned short tile[64][65];
  const int k0 = blockIdx.y * 64, n0 = blockIdx.x * 64;
  const int tid = threadIdx.x;
  const int r = tid >> 4, c4 = tid & 15;
#pragma unroll
  for (int p = 0; p < 4; ++p) {
    int row = p * 16 + r;
    float4 v = *(const float4*)(in + (size_t)(k0 + row) * N + n0 + c4 * 4);
    tile[c4 * 4 + 0][row] = f2b(v.x);
    tile[c4 * 4 + 1][row] = f2b(v.y);
    tile[c4 * 4 + 2][row] = f2b(v.z);
    tile[c4 * 4 + 3][row] = f2b(v.w);
  }
  __syncthreads();
#pragma unroll
  for (int p = 0; p < 4; ++p) {
    int nr = p * 16 + r;
    ushort4 o;
    o.x = tile[nr][c4 * 4 + 0];
    o.y = tile[nr][c4 * 4 + 1];
    o.z = tile[nr][c4 * 4 + 2];
    o.w = tile[nr][c4 * 4 + 3];
    *(ushort4*)(out + (size_t)(n0 + nr) * K + k0 + c4 * 4) = o;
  }
}

// ---------- GEMM v2 (R5-proven): C[M,N] = A[M,K] @ BT[N,K]^T ----------
// 128x128 tile, BK=64, double-buffered LDS (64KB), one barrier per k-step,
// XOR-swizzled staging (pre-swizzled global source, linear LDS dest).
__global__ __launch_bounds__(256) void gemm_bt(
    const unsigned short* __restrict__ A, const unsigned short* __restrict__ BT,
    unsigned short* __restrict__ Cb, float* __restrict__ Cf, int M, int N, int K,
    float cscale) {
  __shared__ __align__(16) unsigned short sA[2][128 * 64];
  __shared__ __align__(16) unsigned short sB[2][128 * 64];
  const int tid = threadIdx.x;
  const int wave = tid >> 6, lane = tid & 63;
  const int quad = lane >> 4, cl = lane & 15;
  const int m0 = blockIdx.y * 128, n0 = blockIdx.x * 128;
  const int wm = (wave >> 1) * 64, wn = (wave & 1) * 64;
  (void)M;

  f32x4 acc[4][4] = {};

  const int lr = lane >> 3;
  const int lc = (lane & 7) ^ lr;
  const unsigned short* gA = A + (size_t)(m0 + wave * 32 + lr) * K + lc * 8;
  const unsigned short* gB = BT + (size_t)(n0 + wave * 32 + lr) * K + lc * 8;
  const int nk = K >> 6;

#pragma unroll
  for (int r = 0; r < 4; ++r) {
    async16(gA + (size_t)r * 8 * K, (char*)sA[0] + (wave * 32 + r * 8) * 128);
    async16(gB + (size_t)r * 8 * K, (char*)sB[0] + (wave * 32 + r * 8) * 128);
  }
  __syncthreads();

  for (int kt = 0; kt < nk; ++kt) {
    const int cur = kt & 1;
    if (kt + 1 < nk) {
      const int k1 = (kt + 1) * 64;
#pragma unroll
      for (int r = 0; r < 4; ++r) {
        async16(gA + (size_t)r * 8 * K + k1,
                (char*)sA[cur ^ 1] + (wave * 32 + r * 8) * 128);
        async16(gB + (size_t)r * 8 * K + k1,
                (char*)sB[cur ^ 1] + (wave * 32 + r * 8) * 128);
      }
    }
    const char* cA = (const char*)sA[cur];
    const char* cB = (const char*)sB[cur];
#pragma unroll
    for (int kk = 0; kk < 2; ++kk) {
      const int g = kk * 4 + quad;
      bf16x8 af[4], bfr[4];
#pragma unroll
      for (int i = 0; i < 4; ++i) {
        int row = wm + i * 16 + cl;
        af[i] = *(const bf16x8*)(cA + row * 128 + (g ^ (cl & 7)) * 16);
      }
#pragma unroll
      for (int j = 0; j < 4; ++j) {
        int row = wn + j * 16 + cl;
        bfr[j] = *(const bf16x8*)(cB + row * 128 + (g ^ (cl & 7)) * 16);
      }
#pragma unroll
      for (int i = 0; i < 4; ++i)
#pragma unroll
        for (int j = 0; j < 4; ++j)
          acc[i][j] = __builtin_amdgcn_mfma_f32_16x16x32_bf16(af[i], bfr[j], acc[i][j], 0, 0, 0);
    }
    __syncthreads();
  }
#pragma unroll
  for (int i = 0; i < 4; ++i)
#pragma unroll
    for (int j = 0; j < 4; ++j)
#pragma unroll
      for (int r = 0; r < 4; ++r) {
        int row = m0 + wm + i * 16 + quad * 4 + r;
        int col = n0 + wn + j * 16 + cl;
        float v = acc[i][j][r];
        if (Cb) Cb[(size_t)row * N + col] = f2b(v * cscale);
        if (Cf) Cf[(size_t)row * N + col] = v;
      }
}

// ---------- fused Q+c projection GEMM (R5 v2 body) ----------
__global__ __launch_bounds__(256) void gemm_qc(
    const unsigned short* __restrict__ A, const unsigned short* __restrict__ BT,
    unsigned short* __restrict__ Qb, unsigned short* __restrict__ cb,
    float* __restrict__ cout, int K, float qscale) {
  __shared__ __align__(16) unsigned short sA[2][128 * 64];
  __shared__ __align__(16) unsigned short sB[2][128 * 64];
  const int tid = threadIdx.x;
  const int wave = tid >> 6, lane = tid & 63;
  const int quad = lane >> 4, cl = lane & 15;
  const int m0 = blockIdx.y * 128, n0 = blockIdx.x * 128;
  const int wm = (wave >> 1) * 64, wn = (wave & 1) * 64;

  f32x4 acc[4][4] = {};

  const int lr = lane >> 3;
  const int lc = (lane & 7) ^ lr;
  const unsigned short* gA = A + (size_t)(m0 + wave * 32 + lr) * K + lc * 8;
  const unsigned short* gB = BT + (size_t)(n0 + wave * 32 + lr) * K + lc * 8;
  const int nk = K >> 6;

#pragma unroll
  for (int r = 0; r < 4; ++r) {
    async16(gA + (size_t)r * 8 * K, (char*)sA[0] + (wave * 32 + r * 8) * 128);
    async16(gB + (size_t)r * 8 * K, (char*)sB[0] + (wave * 32 + r * 8) * 128);
  }
  __syncthreads();

  for (int kt = 0; kt < nk; ++kt) {
    const int cur = kt & 1;
    if (kt + 1 < nk) {
      const int k1 = (kt + 1) * 64;
#pragma unroll
      for (int r = 0; r < 4; ++r) {
        async16(gA + (size_t)r * 8 * K + k1,
                (char*)sA[cur ^ 1] + (wave * 32 + r * 8) * 128);
        async16(gB + (size_t)r * 8 * K + k1,
                (char*)sB[cur ^ 1] + (wave * 32 + r * 8) * 128);
      }
    }
    const char* cA = (const char*)sA[cur];
    const char* cB = (const char*)sB[cur];
#pragma unroll
    for (int kk = 0; kk < 2; ++kk) {
      const int g = kk * 4 + quad;
      bf16x8 af[4], bfr[4];
#pragma unroll
      for (int i = 0; i < 4; ++i) {
        int row = wm + i * 16 + cl;
        af[i] = *(const bf16x8*)(cA + row * 128 + (g ^ (cl & 7)) * 16);
      }
#pragma unroll
      for (int j = 0; j < 4; ++j) {
        int row = wn + j * 16 + cl;
        bfr[j] = *(const bf16x8*)(cB + row * 128 + (g ^ (cl & 7)) * 16);
      }
#pragma unroll
      for (int i = 0; i < 4; ++i)
#pragma unroll
        for (int j = 0; j < 4; ++j)
          acc[i][j] = __builtin_amdgcn_mfma_f32_16x16x32_bf16(af[i], bfr[j], acc[i][j], 0, 0, 0);
    }
    __syncthreads();
  }
  const bool qreg = (n0 < 2048);
#pragma unroll
  for (int i = 0; i < 4; ++i)
#pragma unroll
    for (int j = 0; j < 4; ++j)
#pragma unroll
      for (int r = 0; r < 4; ++r) {
        int row = m0 + wm + i * 16 + quad * 4 + r;
        int col = n0 + wn + j * 16 + cl;
        float v = acc[i][j][r];
        if (qreg) {
          Qb[(size_t)row * 2048 + col] = f2b(v * qscale);
        } else {
          int c2 = col - 2048;
          cb[(size_t)row * 512 + c2] = f2b(v);
          cout[(size_t)row * 512 + c2] = v;
        }
      }
}

// ---------- merged K-proj + V^T-proj (one 1024-block launch, 2 full rounds) ----------
// f<512 : Kb[4096,2048] = cb[4096,512] @ WkT[2048,512]^T   (m0=(f>>4)*128, n0=(f&15)*128)
// f>=512: VT[2048,4096] = WvT[2048,512] @ cb[4096,512]^T   (g=f-512; m0=(g>>5)*128, n0=(g&31)*128)
// Removes one launch serialization point; both depend only on cb.
__global__ __launch_bounds__(256) void gemm_kv(
    const unsigned short* __restrict__ cb, const unsigned short* __restrict__ WkT,
    const unsigned short* __restrict__ WvT, unsigned short* __restrict__ Kb,
    unsigned short* __restrict__ VT) {
  __shared__ __align__(16) unsigned short sA[2][128 * 64];
  __shared__ __align__(16) unsigned short sB[2][128 * 64];
  const int tid = threadIdx.x;
  const int wave = tid >> 6, lane = tid & 63;
  const int quad = lane >> 4, cl = lane & 15;
  const int wm = (wave >> 1) * 64, wn = (wave & 1) * 64;
  const int K = 512;

  const unsigned short *A, *BT;
  unsigned short* C;
  int N, m0, n0;
  const int f = blockIdx.x;
  if (f < 512) {
    A = cb; BT = WkT; C = Kb; N = 2048;
    m0 = (f >> 4) * 128; n0 = (f & 15) * 128;
  } else {
    const int g2 = f - 512;
    A = WvT; BT = cb; C = VT; N = 4096;
    m0 = (g2 >> 5) * 128; n0 = (g2 & 31) * 128;
  }

  f32x4 acc[4][4] = {};

  const int lr = lane >> 3;
  const int lc = (lane & 7) ^ lr;
  const unsigned short* gA = A + (size_t)(m0 + wave * 32 + lr) * K + lc * 8;
  const unsigned short* gB = BT + (size_t)(n0 + wave * 32 + lr) * K + lc * 8;
  const int nk = K >> 6;  // 8

#pragma unroll
  for (int r = 0; r < 4; ++r) {
    async16(gA + (size_t)r * 8 * K, (char*)sA[0] + (wave * 32 + r * 8) * 128);
    async16(gB + (size_t)r * 8 * K, (char*)sB[0] + (wave * 32 + r * 8) * 128);
  }
  __syncthreads();

  for (int kt = 0; kt < nk; ++kt) {
    const int cur = kt & 1;
    if (kt + 1 < nk) {
      const int k1 = (kt + 1) * 64;
#pragma unroll
      for (int r = 0; r < 4; ++r) {
        async16(gA + (size_t)r * 8 * K + k1,
                (char*)sA[cur ^ 1] + (wave * 32 + r * 8) * 128);
        async16(gB + (size_t)r * 8 * K + k1,
                (char*)sB[cur ^ 1] + (wave * 32 + r * 8) * 128);
      }
    }
    const char* cA = (const char*)sA[cur];
    const char* cB = (const char*)sB[cur];
#pragma unroll
    for (int kk = 0; kk < 2; ++kk) {
      const int g = kk * 4 + quad;
      bf16x8 af[4], bfr[4];
#pragma unroll
      for (int i = 0; i < 4; ++i) {
        int row = wm + i * 16 + cl;
        af[i] = *(const bf16x8*)(cA + row * 128 + (g ^ (cl & 7)) * 16);
      }
#pragma unroll
      for (int j = 0; j < 4; ++j) {
        int row = wn + j * 16 + cl;
        bfr[j] = *(const bf16x8*)(cB + row * 128 + (g ^ (cl & 7)) * 16);
      }
#pragma unroll
      for (int i = 0; i < 4; ++i)
#pragma unroll
        for (int j = 0; j < 4; ++j)
          acc[i][j] = __builtin_amdgcn_mfma_f32_16x16x32_bf16(af[i], bfr[j], acc[i][j], 0, 0, 0);
    }
    __syncthreads();
  }
#pragma unroll
  for (int i = 0; i < 4; ++i)
#pragma unroll
    for (int j = 0; j < 4; ++j)
#pragma unroll
      for (int r = 0; r < 4; ++r) {
        int row = m0 + wm + i * 16 + quad * 4 + r;
        int col = n0 + wn + j * 16 + cl;
        C[(size_t)row * N + col] = f2b(acc[i][j][r]);
      }
}

// ---------- flash-style causal attention, v8 ----------
// vs v7 (98.2us): ONE barrier per k-tile (was 2). V now double-buffered
// (LDS 72KB = 2x16K sK + 2x16K sVT + 8K sP; 2x72=144<=160 keeps 2 blocks/CU)
// and its staging issued AFTER B1 -> B2 is provably unnecessary:
//  - sP is wave-local (each wave writes/reads only its own 16 rows).
//  - K[kt+1] -> sK[cur^1] (QK^T reads sK[cur]); any wave issuing it has
//    passed B1(kt-1), so all waves finished QK^T(kt-1) on sK[cur^1]. OK.
//  - V[kt+1] -> sVT[cur^1] issued after B1(kt); PV(kt) reads sVT[cur]. A
//    wave at this issue passed B1(kt) => all waves completed PV(kt-1) on
//    sVT[cur^1] (which preceded their B1(kt) arrival). OK.
//  - V[kt+1] drains at B1(kt+1), before PV(kt+1) reads it (full-tile cover).
// Phase boundary: leading barrier before prologue staging protects the last
// tile's PV reads. setprio REMOVED (R3 95.4 -> R5 98.2 regression; m190).
// XCD swizzle: flat id f -> XCD c=f&7 handles (h,b) groups 4c..4c+3 only,
// so each group's 16 q-blocks share one XCD's L2 (K/V = 2MB/group reused).
__global__ __launch_bounds__(256) void mla_attn(
    const unsigned short* __restrict__ Qm, const unsigned short* __restrict__ Km,
    const unsigned short* __restrict__ Vt, unsigned short* __restrict__ Om, int T) {
  const int ld = 2048;
  const int ldv = 4096;  // B*T
  __shared__ __align__(16) unsigned short sK[2][64 * 128];   // [t][d] xor-swizzled
  __shared__ __align__(16) unsigned short sVT[2][128 * 64];  // [d][t] xor-swizzled
  __shared__ __align__(16) unsigned short sP[64 * 64];       // [q][t] swz(q)-swizzled
  // XCD-aware remap (bijective): f=0..511 -> (h,b,q-pair)
  const int f = blockIdx.x + 16 * blockIdx.y + 256 * blockIdx.z;
  const int c8 = f & 7, jj = f >> 3;
  const int g = c8 * 4 + (jj >> 4);   // 0..31 (h,b) group
  const int bxr = jj & 15;            // q-pair index
  const int h = g & 15, b = g >> 4;
  const int tid = threadIdx.x, wave = tid >> 6, lane = tid & 63;
  const int quad = lane >> 4, cl = lane & 15;
  const int nq = T / 64;  // 32

  for (int phase = 0; phase < 2; ++phase) {
    const int qt = phase ? (nq - 1 - bxr) : bxr;

    // Q A-fragments in registers (pre-scaled by 1/sqrt(Dh)*log2e in Q-GEMM)
    bf16x8 qf[4];
    {
      const unsigned short* Qg =
          Qm + (size_t)(b * T + qt * 64 + wave * 16 + cl) * ld + h * 128 + quad * 8;
#pragma unroll
      for (int kk = 0; kk < 4; ++kk)
        qf[kk] = *(const bf16x8*)(Qg + kk * 32);
    }

    float m_i[4], l_part[4];
    f32x4 acc_o[8] = {};
#pragma unroll
    for (int r = 0; r < 4; ++r) { m_i[r] = -1e30f; l_part[r] = 0.f; }

    const unsigned short* Kg0 = Km + (size_t)(b * T) * ld + h * 128;
    const unsigned short* Vg0 = Vt + (size_t)(h * 128) * ldv + (size_t)b * T;

    // prologue: all waves done with prior-phase LDS reads, then stage K[0],V[0]
    __syncthreads();
#pragma unroll
    for (int r = 0; r < 4; ++r) {
      int c0 = r * 256 + wave * 64;
      int c = c0 + lane;
      int row = c >> 4, j = (c & 15) ^ (row & 7);
      async16(Kg0 + (size_t)row * ld + j * 8, (char*)sK[0] + c0 * 16);
      int d = c >> 3, jv = (c & 7) ^ (d & 7);
      async16(Vg0 + (size_t)d * ldv + jv * 8, (char*)sVT[0] + c0 * 16);
    }
    __syncthreads();  // drain K[0], V[0]

    for (int kt = 0; kt <= qt; ++kt) {
      const int cur = kt & 1;
      const char* cK = (const char*)sK[cur];
      const char* cV = (const char*)sVT[cur];

      // issue next K tile (overlaps QK^T on sK[cur]; drained at B1 below)
      if (kt < qt) {
        const unsigned short* Kg = Kg0 + (size_t)(kt + 1) * 64 * ld;
        char* dK = (char*)sK[cur ^ 1];
#pragma unroll
        for (int r = 0; r < 4; ++r) {
          int c0 = r * 256 + wave * 64;
          int c = c0 + lane;
          int row = c >> 4, j = (c & 15) ^ (row & 7);
          async16(Kg + (size_t)row * ld + j * 8, dK + c0 * 16);
        }
      }

      // S = Q @ K^T : 16 q-rows (this wave) x 64 keys (exp2 domain, pre-scaled)
      f32x4 s[4] = {};
#pragma unroll
      for (int kk = 0; kk < 4; ++kk) {
#pragma unroll
        for (int j = 0; j < 4; ++j) {
          int t = j * 16 + cl;
          int jp = (kk * 4 + quad) ^ (t & 7);
          bf16x8 bk = *(const bf16x8*)(cK + (t * 16 + jp) * 16);
          s[j] = __builtin_amdgcn_mfma_f32_16x16x32_bf16(qf[kk], bk, s[j], 0, 0, 0);
        }
      }

      // causal mask + online softmax (deferred max, lane-local fast path)
      const bool need_mask = (kt == qt);
#pragma unroll
      for (int r = 0; r < 4; ++r) {
        int q_l = wave * 16 + quad * 4 + r;
        float mxl = -1e30f;
#pragma unroll
        for (int j = 0; j < 4; ++j) {
          float v = s[j][r];
          if (need_mask) {
            int t_l = j * 16 + cl;
            if (t_l > q_l) v = -1e30f;
            s[j][r] = v;
          }
          mxl = fmaxf(mxl, v);
        }
        if (__any(mxl > m_i[r] + 6.f)) {
          float mx = mxl;
#pragma unroll
          for (int off = 1; off < 16; off <<= 1)
            mx = fmaxf(mx, __shfl_xor(mx, off));
          float m_new = fmaxf(m_i[r], mx);
          float alpha = exp2f(m_i[r] - m_new);
          m_i[r] = m_new;
          l_part[r] *= alpha;
#pragma unroll
          for (int jd = 0; jd < 8; ++jd)
            acc_o[jd][r] *= alpha;
        }
        float rs = 0.f;
#pragma unroll
        for (int j = 0; j < 4; ++j) {
          float p = exp2f(s[j][r] - m_i[r]);
          s[j][r] = p;
          rs += p;
        }
        l_part[r] += rs;  // per-lane partial; cross-lane reduce in epilogue
      }

      // write P swizzled into sP (wave-local rows -> no barrier needed)
#pragma unroll
      for (int j = 0; j < 4; ++j)
#pragma unroll
        for (int r = 0; r < 4; ++r) {
          int q = wave * 16 + quad * 4 + r;
          int swz = (q & 7) ^ (((q >> 3) & 1) << 1);
          int t = j * 16 + cl;
          int jp = (t >> 3) ^ swz;
          sP[(q * 8 + jp) * 8 + (t & 7)] = f2b(s[j][r]);
        }

      __syncthreads();  // B1 (only barrier): drains K[kt+1] + V[kt]; all
                        // waves past QK^T(kt) and PV(kt-1)

      // issue next V tile into the other buffer (drains at B1(kt+1);
      // covered by PV(kt) + whole next tile's QK^T+softmax)
      if (kt < qt) {
        const unsigned short* Vg = Vg0 + (kt + 1) * 64;
        char* dV = (char*)sVT[cur ^ 1];
#pragma unroll
        for (int r = 0; r < 4; ++r) {
          int c0 = r * 256 + wave * 64;
          int c = c0 + lane;
          int d = c >> 3, jv = (c & 7) ^ (d & 7);
          async16(Vg + (size_t)d * ldv + jv * 8, dV + c0 * 16);
        }
      }

      // O += P @ V (A from own-wave sP rows, B from sVT[cur]; both b128)
#pragma unroll
      for (int kk2 = 0; kk2 < 2; ++kk2) {
        int q = wave * 16 + cl;
        int swz = (q & 7) ^ (((q >> 3) & 1) << 1);
        int jp = (kk2 * 4 + quad) ^ swz;
        bf16x8 ap = *(const bf16x8*)((const char*)sP + (q * 8 + jp) * 16);
#pragma unroll
        for (int jd = 0; jd < 8; ++jd) {
          int d = jd * 16 + cl;
          int jpv = (kk2 * 4 + quad) ^ (d & 7);
          bf16x8 bv = *(const bf16x8*)(cV + (d * 8 + jpv) * 16);
          acc_o[jd] = __builtin_amdgcn_mfma_f32_16x16x32_bf16(ap, bv, acc_o[jd], 0, 0, 0);
        }
      }
      // no B2: next tile's K-stage targets sK[cur^1], next V-stage is
      // issued only after B1(kt+1) — race-free per header analysis.
    }

    // epilogue: reduce l partials across the 16 row lanes, normalize, store
#pragma unroll
    for (int r = 0; r < 4; ++r) {
      float l = l_part[r];
#pragma unroll
      for (int off = 1; off < 16; off <<= 1)
        l += __shfl_xor(l, off);
      float inv = 1.f / l;
      int row = b * T + qt * 64 + wave * 16 + quad * 4 + r;
#pragma unroll
      for (int jd = 0; jd < 8; ++jd)
        Om[(size_t)row * ld + h * 128 + jd * 16 + cl] = f2b(acc_o[jd][r] * inv);
    }
  }
}

// ---------- launch ----------
extern "C" void kernel_launch(void* const* d_in, const int* in_sizes, int n_in,
                              void* d_out, int out_size, void* d_ws, size_t ws_size,
                              hipStream_t stream) {
  (void)in_sizes; (void)n_in; (void)out_size; (void)ws_size;
  const int B = 2, T = 2048, Dm = 2048, H = 16, Dh = 128, R = 512;
  const int M = B * T;  // 4096
  const float* x     = (const float*)d_in[0];
  const float* Wq    = (const float*)d_in[1];
  const float* Wdown = (const float*)d_in[2];
  const float* Wkup  = (const float*)d_in[3];
  const float* Wvup  = (const float*)d_in[4];
  const float* Wo    = (const float*)d_in[5];

  float* out  = (float*)d_out;                      // (B*T) x 2048 fp32
  float* cout = out + (size_t)M * Dm;               // (B*T) x 512  fp32

  unsigned short* ws  = (unsigned short*)d_ws;      // bf16 scratch
  unsigned short* WqT = ws;                         // 2048x2048 (stacked B rows 0..2047)
  unsigned short* WdT = WqT + (size_t)Dm * Dm;      // 512x2048  (stacked B rows 2048..2559)
  unsigned short* WoT = WdT + (size_t)R * Dm;       // 2048x2048
  unsigned short* WkT = WoT + (size_t)Dm * Dm;      // 2048x512
  unsigned short* WvT = WkT + (size_t)Dm * R;       // 2048x512
  unsigned short* xb  = WvT + (size_t)Dm * R;       // 4096x2048 (reused as AO)
  unsigned short* cb  = xb + (size_t)M * Dm;        // 4096x512
  unsigned short* Qb  = cb + (size_t)M * R;         // 4096x2048
  unsigned short* Kb  = Qb + (size_t)M * Dm;        // 4096x2048
  unsigned short* VT  = Kb + (size_t)M * Dm;        // 2048x4096 (V^T, d-major)
  unsigned short* AO  = xb;                         // alias: xb dead after Q-proj

  // softmax scale folded into Q: 1/sqrt(128) * log2(e)
  const float qscale = 0.08838834764831845f * 1.4426950408889634f;

  // input casts / weight transposes -> bf16 BT form
  cast_f32_bf16<<<(M * Dm) / 1024, 256, 0, stream>>>(x, xb, M * Dm);
  transpose_cast<<<dim3(32, 32), 256, 0, stream>>>(Wq, WqT, Dm, Dm);
  transpose_cast<<<dim3(8, 32), 256, 0, stream>>>(Wdown, WdT, Dm, R);
  transpose_cast<<<dim3(32, 32), 256, 0, stream>>>(Wo, WoT, Dm, Dm);
  transpose_cast<<<dim3(32, 8), 256, 0, stream>>>(Wkup, WkT, R, Dm);
  transpose_cast<<<dim3(32, 8), 256, 0, stream>>>(Wvup, WvT, R, Dm);

  // fused Q + c projection: grid (2560/128, 4096/128) = (20,32) = 640 blocks
  gemm_qc<<<dim3(20, 32), 256, 0, stream>>>(xb, WqT, Qb, cb, cout, Dm, qscale);

  // merged K-proj + V^T-proj: 1024 blocks = exactly 2 residency rounds
  gemm_kv<<<1024, 256, 0, stream>>>(cb, WkT, WvT, Kb, VT);

  // causal attention: balanced pair per block, XCD-swizzled
  mla_attn<<<dim3(T / 128, H, B), 256, 0, stream>>>(Qb, Kb, VT, AO, T);

  // output projection (fp32 out)
  gemm_bt<<<dim3(Dm / 128, M / 128), 256, 0, stream>>>(AO, WoT, nullptr, out, M, Dm, Dm, 1.f);
  (void)Dh; (void)H;
}

// Round 8
// 401.093 us; speedup vs baseline: 1.0302x; 1.0302x over previous
//
#include <hip/hip_runtime.h>

// ---------- common helpers ----------
typedef short bf16x8 __attribute__((ext_vector_type(8)));
typedef float f32x4 __attribute__((ext_vector_type(4)));

__device__ __forceinline__ void async16(const void* g, const void* l) {
  __builtin_amdgcn_global_load_lds(
      (const __attribute__((address_space(1))) unsigned int*)g,
      (__attribute__((address_space(3))) unsigned int*)(void*)(uintptr_t)l,
      16, 0, 0);
}

__device__ __forceinline__ unsigned short f2b(float f) {
  unsigned int u = __float_as_uint(f);
  u += 0x7fffu + ((u >> 16) & 1u);   // round-to-nearest-even
  return (unsigned short)(u >> 16);
}

// ---------- cast fp32 -> bf16, n % 1024 == 0 ----------
__global__ __launch_bounds__(256) void cast_f32_bf16(
    const float* __restrict__ in, unsigned short* __restrict__ out, int n) {
  int i = (blockIdx.x * 256 + threadIdx.x) * 4;
  if (i < n) {
    float4 v = *(const float4*)(in + i);
    ushort4 o;
    o.x = f2b(v.x); o.y = f2b(v.y); o.z = f2b(v.z); o.w = f2b(v.w);
    *(ushort4*)(out + i) = o;
  }
}

// ---------- transpose+cast: out_bf16[N][K] = in_f32[K][N], K,N multiples of 64 ----------
__global__ __launch_bounds__(256) void transpose_cast(
    const float* __restrict__ in, unsigned short* __restrict__ out,
    int K, int N) {
  __shared__ __align__(16) unsigned short tile[64][65];
  const int k0 = blockIdx.y * 64, n0 = blockIdx.x * 64;
  const int tid = threadIdx.x;
  const int r = tid >> 4, c4 = tid & 15;
#pragma unroll
  for (int p = 0; p < 4; ++p) {
    int row = p * 16 + r;
    float4 v = *(const float4*)(in + (size_t)(k0 + row) * N + n0 + c4 * 4);
    tile[c4 * 4 + 0][row] = f2b(v.x);
    tile[c4 * 4 + 1][row] = f2b(v.y);
    tile[c4 * 4 + 2][row] = f2b(v.z);
    tile[c4 * 4 + 3][row] = f2b(v.w);
  }
  __syncthreads();
#pragma unroll
  for (int p = 0; p < 4; ++p) {
    int nr = p * 16 + r;
    ushort4 o;
    o.x = tile[nr][c4 * 4 + 0];
    o.y = tile[nr][c4 * 4 + 1];
    o.z = tile[nr][c4 * 4 + 2];
    o.w = tile[nr][c4 * 4 + 3];
    *(ushort4*)(out + (size_t)(n0 + nr) * K + k0 + c4 * 4) = o;
  }
}

// ---------- GEMM v2 (R5-proven): C[M,N] = A[M,K] @ BT[N,K]^T ----------
// 128x128 tile, BK=64, double-buffered LDS (64KB), one barrier per k-step,
// XOR-swizzled staging (pre-swizzled global source, linear LDS dest).
__global__ __launch_bounds__(256) void gemm_bt(
    const unsigned short* __restrict__ A, const unsigned short* __restrict__ BT,
    unsigned short* __restrict__ Cb, float* __restrict__ Cf, int M, int N, int K,
    float cscale) {
  __shared__ __align__(16) unsigned short sA[2][128 * 64];
  __shared__ __align__(16) unsigned short sB[2][128 * 64];
  const int tid = threadIdx.x;
  const int wave = tid >> 6, lane = tid & 63;
  const int quad = lane >> 4, cl = lane & 15;
  const int m0 = blockIdx.y * 128, n0 = blockIdx.x * 128;
  const int wm = (wave >> 1) * 64, wn = (wave & 1) * 64;
  (void)M;

  f32x4 acc[4][4] = {};

  const int lr = lane >> 3;
  const int lc = (lane & 7) ^ lr;
  const unsigned short* gA = A + (size_t)(m0 + wave * 32 + lr) * K + lc * 8;
  const unsigned short* gB = BT + (size_t)(n0 + wave * 32 + lr) * K + lc * 8;
  const int nk = K >> 6;

#pragma unroll
  for (int r = 0; r < 4; ++r) {
    async16(gA + (size_t)r * 8 * K, (char*)sA[0] + (wave * 32 + r * 8) * 128);
    async16(gB + (size_t)r * 8 * K, (char*)sB[0] + (wave * 32 + r * 8) * 128);
  }
  __syncthreads();

  for (int kt = 0; kt < nk; ++kt) {
    const int cur = kt & 1;
    if (kt + 1 < nk) {
      const int k1 = (kt + 1) * 64;
#pragma unroll
      for (int r = 0; r < 4; ++r) {
        async16(gA + (size_t)r * 8 * K + k1,
                (char*)sA[cur ^ 1] + (wave * 32 + r * 8) * 128);
        async16(gB + (size_t)r * 8 * K + k1,
                (char*)sB[cur ^ 1] + (wave * 32 + r * 8) * 128);
      }
    }
    const char* cA = (const char*)sA[cur];
    const char* cB = (const char*)sB[cur];
#pragma unroll
    for (int kk = 0; kk < 2; ++kk) {
      const int g = kk * 4 + quad;
      bf16x8 af[4], bfr[4];
#pragma unroll
      for (int i = 0; i < 4; ++i) {
        int row = wm + i * 16 + cl;
        af[i] = *(const bf16x8*)(cA + row * 128 + (g ^ (cl & 7)) * 16);
      }
#pragma unroll
      for (int j = 0; j < 4; ++j) {
        int row = wn + j * 16 + cl;
        bfr[j] = *(const bf16x8*)(cB + row * 128 + (g ^ (cl & 7)) * 16);
      }
#pragma unroll
      for (int i = 0; i < 4; ++i)
#pragma unroll
        for (int j = 0; j < 4; ++j)
          acc[i][j] = __builtin_amdgcn_mfma_f32_16x16x32_bf16(af[i], bfr[j], acc[i][j], 0, 0, 0);
    }
    __syncthreads();
  }
#pragma unroll
  for (int i = 0; i < 4; ++i)
#pragma unroll
    for (int j = 0; j < 4; ++j)
#pragma unroll
      for (int r = 0; r < 4; ++r) {
        int row = m0 + wm + i * 16 + quad * 4 + r;
        int col = n0 + wn + j * 16 + cl;
        float v = acc[i][j][r];
        if (Cb) Cb[(size_t)row * N + col] = f2b(v * cscale);
        if (Cf) Cf[(size_t)row * N + col] = v;
      }
}

// ---------- fused Q+c projection GEMM (R5 v2 body) ----------
__global__ __launch_bounds__(256) void gemm_qc(
    const unsigned short* __restrict__ A, const unsigned short* __restrict__ BT,
    unsigned short* __restrict__ Qb, unsigned short* __restrict__ cb,
    float* __restrict__ cout, int K, float qscale) {
  __shared__ __align__(16) unsigned short sA[2][128 * 64];
  __shared__ __align__(16) unsigned short sB[2][128 * 64];
  const int tid = threadIdx.x;
  const int wave = tid >> 6, lane = tid & 63;
  const int quad = lane >> 4, cl = lane & 15;
  const int m0 = blockIdx.y * 128, n0 = blockIdx.x * 128;
  const int wm = (wave >> 1) * 64, wn = (wave & 1) * 64;

  f32x4 acc[4][4] = {};

  const int lr = lane >> 3;
  const int lc = (lane & 7) ^ lr;
  const unsigned short* gA = A + (size_t)(m0 + wave * 32 + lr) * K + lc * 8;
  const unsigned short* gB = BT + (size_t)(n0 + wave * 32 + lr) * K + lc * 8;
  const int nk = K >> 6;

#pragma unroll
  for (int r = 0; r < 4; ++r) {
    async16(gA + (size_t)r * 8 * K, (char*)sA[0] + (wave * 32 + r * 8) * 128);
    async16(gB + (size_t)r * 8 * K, (char*)sB[0] + (wave * 32 + r * 8) * 128);
  }
  __syncthreads();

  for (int kt = 0; kt < nk; ++kt) {
    const int cur = kt & 1;
    if (kt + 1 < nk) {
      const int k1 = (kt + 1) * 64;
#pragma unroll
      for (int r = 0; r < 4; ++r) {
        async16(gA + (size_t)r * 8 * K + k1,
                (char*)sA[cur ^ 1] + (wave * 32 + r * 8) * 128);
        async16(gB + (size_t)r * 8 * K + k1,
                (char*)sB[cur ^ 1] + (wave * 32 + r * 8) * 128);
      }
    }
    const char* cA = (const char*)sA[cur];
    const char* cB = (const char*)sB[cur];
#pragma unroll
    for (int kk = 0; kk < 2; ++kk) {
      const int g = kk * 4 + quad;
      bf16x8 af[4], bfr[4];
#pragma unroll
      for (int i = 0; i < 4; ++i) {
        int row = wm + i * 16 + cl;
        af[i] = *(const bf16x8*)(cA + row * 128 + (g ^ (cl & 7)) * 16);
      }
#pragma unroll
      for (int j = 0; j < 4; ++j) {
        int row = wn + j * 16 + cl;
        bfr[j] = *(const bf16x8*)(cB + row * 128 + (g ^ (cl & 7)) * 16);
      }
#pragma unroll
      for (int i = 0; i < 4; ++i)
#pragma unroll
        for (int j = 0; j < 4; ++j)
          acc[i][j] = __builtin_amdgcn_mfma_f32_16x16x32_bf16(af[i], bfr[j], acc[i][j], 0, 0, 0);
    }
    __syncthreads();
  }
  const bool qreg = (n0 < 2048);
#pragma unroll
  for (int i = 0; i < 4; ++i)
#pragma unroll
    for (int j = 0; j < 4; ++j)
#pragma unroll
      for (int r = 0; r < 4; ++r) {
        int row = m0 + wm + i * 16 + quad * 4 + r;
        int col = n0 + wn + j * 16 + cl;
        float v = acc[i][j][r];
        if (qreg) {
          Qb[(size_t)row * 2048 + col] = f2b(v * qscale);
        } else {
          int c2 = col - 2048;
          cb[(size_t)row * 512 + c2] = f2b(v);
          cout[(size_t)row * 512 + c2] = v;
        }
      }
}

// ---------- merged K-proj + V^T-proj (one 1024-block launch) ----------
// f<512 : Kb[4096,2048] = cb[4096,512] @ WkT[2048,512]^T
// f>=512: VT[2048,4096] = WvT[2048,512] @ cb[4096,512]^T
__global__ __launch_bounds__(256) void gemm_kv(
    const unsigned short* __restrict__ cb, const unsigned short* __restrict__ WkT,
    const unsigned short* __restrict__ WvT, unsigned short* __restrict__ Kb,
    unsigned short* __restrict__ VT) {
  __shared__ __align__(16) unsigned short sA[2][128 * 64];
  __shared__ __align__(16) unsigned short sB[2][128 * 64];
  const int tid = threadIdx.x;
  const int wave = tid >> 6, lane = tid & 63;
  const int quad = lane >> 4, cl = lane & 15;
  const int wm = (wave >> 1) * 64, wn = (wave & 1) * 64;
  const int K = 512;

  const unsigned short *A, *BT;
  unsigned short* C;
  int N, m0, n0;
  const int f = blockIdx.x;
  if (f < 512) {
    A = cb; BT = WkT; C = Kb; N = 2048;
    m0 = (f >> 4) * 128; n0 = (f & 15) * 128;
  } else {
    const int g2 = f - 512;
    A = WvT; BT = cb; C = VT; N = 4096;
    m0 = (g2 >> 5) * 128; n0 = (g2 & 31) * 128;
  }

  f32x4 acc[4][4] = {};

  const int lr = lane >> 3;
  const int lc = (lane & 7) ^ lr;
  const unsigned short* gA = A + (size_t)(m0 + wave * 32 + lr) * K + lc * 8;
  const unsigned short* gB = BT + (size_t)(n0 + wave * 32 + lr) * K + lc * 8;
  const int nk = K >> 6;  // 8

#pragma unroll
  for (int r = 0; r < 4; ++r) {
    async16(gA + (size_t)r * 8 * K, (char*)sA[0] + (wave * 32 + r * 8) * 128);
    async16(gB + (size_t)r * 8 * K, (char*)sB[0] + (wave * 32 + r * 8) * 128);
  }
  __syncthreads();

  for (int kt = 0; kt < nk; ++kt) {
    const int cur = kt & 1;
    if (kt + 1 < nk) {
      const int k1 = (kt + 1) * 64;
#pragma unroll
      for (int r = 0; r < 4; ++r) {
        async16(gA + (size_t)r * 8 * K + k1,
                (char*)sA[cur ^ 1] + (wave * 32 + r * 8) * 128);
        async16(gB + (size_t)r * 8 * K + k1,
                (char*)sB[cur ^ 1] + (wave * 32 + r * 8) * 128);
      }
    }
    const char* cA = (const char*)sA[cur];
    const char* cB = (const char*)sB[cur];
#pragma unroll
    for (int kk = 0; kk < 2; ++kk) {
      const int g = kk * 4 + quad;
      bf16x8 af[4], bfr[4];
#pragma unroll
      for (int i = 0; i < 4; ++i) {
        int row = wm + i * 16 + cl;
        af[i] = *(const bf16x8*)(cA + row * 128 + (g ^ (cl & 7)) * 16);
      }
#pragma unroll
      for (int j = 0; j < 4; ++j) {
        int row = wn + j * 16 + cl;
        bfr[j] = *(const bf16x8*)(cB + row * 128 + (g ^ (cl & 7)) * 16);
      }
#pragma unroll
      for (int i = 0; i < 4; ++i)
#pragma unroll
        for (int j = 0; j < 4; ++j)
          acc[i][j] = __builtin_amdgcn_mfma_f32_16x16x32_bf16(af[i], bfr[j], acc[i][j], 0, 0, 0);
    }
    __syncthreads();
  }
#pragma unroll
  for (int i = 0; i < 4; ++i)
#pragma unroll
    for (int j = 0; j < 4; ++j)
#pragma unroll
      for (int r = 0; r < 4; ++r) {
        int row = m0 + wm + i * 16 + quad * 4 + r;
        int col = n0 + wn + j * 16 + cl;
        C[(size_t)row * N + col] = f2b(acc[i][j][r]);
      }
}

// ---------- flash-style causal attention, v9 ----------
// = R3's v6 structure EXACTLY (95.4us verified: 56KB LDS -> 2 blocks/CU,
// sK double-buffered, sVT single + B2, no setprio) + R7's XCD remap only
// (pure index transform; R7 proved it cuts FETCH 259MB -> 25MB by making
// each (h,b) group's 16 q-blocks share one XCD's L2).
// R7's 72KB one-barrier variant is DEAD: LDS >= 64KB -> 1 block/CU on this
// chip (R1: 72KB/11%; R7: 72KB/11%; R3/R5: 56KB/20%) and losing the second
// resident block costs more than a barrier saves (rule from R1, confirmed).
__global__ __launch_bounds__(256) void mla_attn(
    const unsigned short* __restrict__ Qm, const unsigned short* __restrict__ Km,
    const unsigned short* __restrict__ Vt, unsigned short* __restrict__ Om, int T) {
  const int ld = 2048;
  const int ldv = 4096;  // B*T
  __shared__ __align__(16) unsigned short sK[2][64 * 128];  // [t][d] xor-swizzled
  __shared__ __align__(16) unsigned short sVT[128 * 64];    // [d][t] xor-swizzled
  __shared__ __align__(16) unsigned short sP[64 * 64];      // [q][t] swz(q)-swizzled
  // XCD-aware remap (bijective): f=0..511; XCD c8=f&7 gets (h,b) groups
  // 4*c8..4*c8+3 -> K/V L2-resident per XCD (R7: FETCH 259->25MB).
  const int f = blockIdx.x + 16 * blockIdx.y + 256 * blockIdx.z;
  const int c8 = f & 7, jj = f >> 3;
  const int g = c8 * 4 + (jj >> 4);   // 0..31 (h,b) group
  const int bxr = jj & 15;            // q-pair index
  const int h = g & 15, b = g >> 4;
  const int tid = threadIdx.x, wave = tid >> 6, lane = tid & 63;
  const int quad = lane >> 4, cl = lane & 15;
  const int nq = T / 64;  // 32

  for (int phase = 0; phase < 2; ++phase) {
    const int qt = phase ? (nq - 1 - bxr) : bxr;

    // Q A-fragments in registers (pre-scaled by 1/sqrt(Dh)*log2e in Q-GEMM)
    bf16x8 qf[4];
    {
      const unsigned short* Qg =
          Qm + (size_t)(b * T + qt * 64 + wave * 16 + cl) * ld + h * 128 + quad * 8;
#pragma unroll
      for (int kk = 0; kk < 4; ++kk)
        qf[kk] = *(const bf16x8*)(Qg + kk * 32);
    }

    float m_i[4], l_part[4];
    f32x4 acc_o[8] = {};
#pragma unroll
    for (int r = 0; r < 4; ++r) { m_i[r] = -1e30f; l_part[r] = 0.f; }

    const unsigned short* Kg0 = Km + (size_t)(b * T) * ld + h * 128;
    const unsigned short* Vg0 = Vt + (size_t)(h * 128) * ldv + (size_t)b * T;

    // prologue: stage K[0] into buffer 0 (prior-phase LDS reads all ended
    // before the prior phase's final B2/B1 barriers).
#pragma unroll
    for (int r = 0; r < 4; ++r) {
      int c0 = r * 256 + wave * 64;
      int c = c0 + lane;
      int row = c >> 4, j = (c & 15) ^ (row & 7);
      async16(Kg0 + (size_t)row * ld + j * 8, (char*)sK[0] + c0 * 16);
    }
    __syncthreads();  // drain K[0] (and phase's Q register loads)

    for (int kt = 0; kt <= qt; ++kt) {
      const int cur = kt & 1;
      const char* cK = (const char*)sK[cur];

      // issue next K tile into the other buffer (overlaps QK^T on sK[cur])
      if (kt < qt) {
        const unsigned short* Kg = Kg0 + (size_t)(kt + 1) * 64 * ld;
        char* dK = (char*)sK[cur ^ 1];
#pragma unroll
        for (int r = 0; r < 4; ++r) {
          int c0 = r * 256 + wave * 64;
          int c = c0 + lane;
          int row = c >> 4, j = (c & 15) ^ (row & 7);
          async16(Kg + (size_t)row * ld + j * 8, dK + c0 * 16);
        }
      }
      // issue this tile's V (prev PV reads of sVT completed at B2)
      {
        const unsigned short* Vg = Vg0 + kt * 64;
#pragma unroll
        for (int r = 0; r < 4; ++r) {
          int c0 = r * 256 + wave * 64;
          int c = c0 + lane;
          int d = c >> 3, jv = (c & 7) ^ (d & 7);
          async16(Vg + (size_t)d * ldv + jv * 8, (char*)sVT + c0 * 16);
        }
      }

      // S = Q @ K^T : 16 q-rows (this wave) x 64 keys (exp2 domain, pre-scaled)
      f32x4 s[4] = {};
#pragma unroll
      for (int kk = 0; kk < 4; ++kk) {
#pragma unroll
        for (int j = 0; j < 4; ++j) {
          int t = j * 16 + cl;
          int jp = (kk * 4 + quad) ^ (t & 7);
          bf16x8 bk = *(const bf16x8*)(cK + (t * 16 + jp) * 16);
          s[j] = __builtin_amdgcn_mfma_f32_16x16x32_bf16(qf[kk], bk, s[j], 0, 0, 0);
        }
      }

      // causal mask + online softmax (deferred max, lane-local fast path)
      const bool need_mask = (kt == qt);
#pragma unroll
      for (int r = 0; r < 4; ++r) {
        int q_l = wave * 16 + quad * 4 + r;
        float mxl = -1e30f;
#pragma unroll
        for (int j = 0; j < 4; ++j) {
          float v = s[j][r];
          if (need_mask) {
            int t_l = j * 16 + cl;
            if (t_l > q_l) v = -1e30f;
            s[j][r] = v;
          }
          mxl = fmaxf(mxl, v);
        }
        if (__any(mxl > m_i[r] + 6.f)) {
          float mx = mxl;
#pragma unroll
          for (int off = 1; off < 16; off <<= 1)
            mx = fmaxf(mx, __shfl_xor(mx, off));
          float m_new = fmaxf(m_i[r], mx);
          float alpha = exp2f(m_i[r] - m_new);
          m_i[r] = m_new;
          l_part[r] *= alpha;
#pragma unroll
          for (int jd = 0; jd < 8; ++jd)
            acc_o[jd][r] *= alpha;
        }
        float rs = 0.f;
#pragma unroll
        for (int j = 0; j < 4; ++j) {
          float p = exp2f(s[j][r] - m_i[r]);
          s[j][r] = p;
          rs += p;
        }
        l_part[r] += rs;  // per-lane partial; cross-lane reduce in epilogue
      }

      // write P swizzled into sP (wave-local rows -> no barrier needed)
#pragma unroll
      for (int j = 0; j < 4; ++j)
#pragma unroll
        for (int r = 0; r < 4; ++r) {
          int q = wave * 16 + quad * 4 + r;
          int swz = (q & 7) ^ (((q >> 3) & 1) << 1);
          int t = j * 16 + cl;
          int jp = (t >> 3) ^ swz;
          sP[(q * 8 + jp) * 8 + (t & 7)] = f2b(s[j][r]);
        }

      __syncthreads();  // B1: drains K[kt+1]+V[kt] (covered); sK[cur] reads done

      // O += P @ V (A from own-wave sP rows, B from sVT; both b128)
#pragma unroll
      for (int kk2 = 0; kk2 < 2; ++kk2) {
        int q = wave * 16 + cl;
        int swz = (q & 7) ^ (((q >> 3) & 1) << 1);
        int jp = (kk2 * 4 + quad) ^ swz;
        bf16x8 ap = *(const bf16x8*)((const char*)sP + (q * 8 + jp) * 16);
#pragma unroll
        for (int jd = 0; jd < 8; ++jd) {
          int d = jd * 16 + cl;
          int jpv = (kk2 * 4 + quad) ^ (d & 7);
          bf16x8 bv = *(const bf16x8*)((const char*)sVT + (d * 8 + jpv) * 16);
          acc_o[jd] = __builtin_amdgcn_mfma_f32_16x16x32_bf16(ap, bv, acc_o[jd], 0, 0, 0);
        }
      }

      __syncthreads();  // B2: pure sync — sVT reads done before next V issue
    }

    // epilogue: reduce l partials across the 16 row lanes, normalize, store
#pragma unroll
    for (int r = 0; r < 4; ++r) {
      float l = l_part[r];
#pragma unroll
      for (int off = 1; off < 16; off <<= 1)
        l += __shfl_xor(l, off);
      float inv = 1.f / l;
      int row = b * T + qt * 64 + wave * 16 + quad * 4 + r;
#pragma unroll
      for (int jd = 0; jd < 8; ++jd)
        Om[(size_t)row * ld + h * 128 + jd * 16 + cl] = f2b(acc_o[jd][r] * inv);
    }
  }
}

// ---------- launch ----------
extern "C" void kernel_launch(void* const* d_in, const int* in_sizes, int n_in,
                              void* d_out, int out_size, void* d_ws, size_t ws_size,
                              hipStream_t stream) {
  (void)in_sizes; (void)n_in; (void)out_size; (void)ws_size;
  const int B = 2, T = 2048, Dm = 2048, H = 16, Dh = 128, R = 512;
  const int M = B * T;  // 4096
  const float* x     = (const float*)d_in[0];
  const float* Wq    = (const float*)d_in[1];
  const float* Wdown = (const float*)d_in[2];
  const float* Wkup  = (const float*)d_in[3];
  const float* Wvup  = (const float*)d_in[4];
  const float* Wo    = (const float*)d_in[5];

  float* out  = (float*)d_out;                      // (B*T) x 2048 fp32
  float* cout = out + (size_t)M * Dm;               // (B*T) x 512  fp32

  unsigned short* ws  = (unsigned short*)d_ws;      // bf16 scratch
  unsigned short* WqT = ws;                         // 2048x2048 (stacked B rows 0..2047)
  unsigned short* WdT = WqT + (size_t)Dm * Dm;      // 512x2048  (stacked B rows 2048..2559)
  unsigned short* WoT = WdT + (size_t)R * Dm;       // 2048x2048
  unsigned short* WkT = WoT + (size_t)Dm * Dm;      // 2048x512
  unsigned short* WvT = WkT + (size_t)Dm * R;       // 2048x512
  unsigned short* xb  = WvT + (size_t)Dm * R;       // 4096x2048 (reused as AO)
  unsigned short* cb  = xb + (size_t)M * Dm;        // 4096x512
  unsigned short* Qb  = cb + (size_t)M * R;         // 4096x2048
  unsigned short* Kb  = Qb + (size_t)M * Dm;        // 4096x2048
  unsigned short* VT  = Kb + (size_t)M * Dm;        // 2048x4096 (V^T, d-major)
  unsigned short* AO  = xb;                         // alias: xb dead after Q-proj

  // softmax scale folded into Q: 1/sqrt(128) * log2(e)
  const float qscale = 0.08838834764831845f * 1.4426950408889634f;

  // input casts / weight transposes -> bf16 BT form
  cast_f32_bf16<<<(M * Dm) / 1024, 256, 0, stream>>>(x, xb, M * Dm);
  transpose_cast<<<dim3(32, 32), 256, 0, stream>>>(Wq, WqT, Dm, Dm);
  transpose_cast<<<dim3(8, 32), 256, 0, stream>>>(Wdown, WdT, Dm, R);
  transpose_cast<<<dim3(32, 32), 256, 0, stream>>>(Wo, WoT, Dm, Dm);
  transpose_cast<<<dim3(32, 8), 256, 0, stream>>>(Wkup, WkT, R, Dm);
  transpose_cast<<<dim3(32, 8), 256, 0, stream>>>(Wvup, WvT, R, Dm);

  // fused Q + c projection: grid (2560/128, 4096/128) = (20,32) = 640 blocks
  gemm_qc<<<dim3(20, 32), 256, 0, stream>>>(xb, WqT, Qb, cb, cout, Dm, qscale);

  // merged K-proj + V^T-proj: 1024 blocks
  gemm_kv<<<1024, 256, 0, stream>>>(cb, WkT, WvT, Kb, VT);

  // causal attention: balanced pair per block, XCD-swizzled
  mla_attn<<<dim3(T / 128, H, B), 256, 0, stream>>>(Qb, Kb, VT, AO, T);

  // output projection (fp32 out)
  gemm_bt<<<dim3(Dm / 128, M / 128), 256, 0, stream>>>(AO, WoT, nullptr, out, M, Dm, Dm, 1.f);
  (void)Dh; (void)H;
}

// Round 9
// 358.480 us; speedup vs baseline: 1.1527x; 1.1189x over previous
//
#include <hip/hip_runtime.h>

// ---------- common helpers ----------
typedef short bf16x8 __attribute__((ext_vector_type(8)));
typedef float f32x4 __attribute__((ext_vector_type(4)));

__device__ __forceinline__ void async16(const void* g, const void* l) {
  __builtin_amdgcn_global_load_lds(
      (const __attribute__((address_space(1))) unsigned int*)g,
      (__attribute__((address_space(3))) unsigned int*)(void*)(uintptr_t)l,
      16, 0, 0);
}

__device__ __forceinline__ unsigned short f2b(float f) {
  unsigned int u = __float_as_uint(f);
  u += 0x7fffu + ((u >> 16) & 1u);   // round-to-nearest-even
  return (unsigned short)(u >> 16);
}

// ---------- cast fp32 -> bf16, n % 1024 == 0 ----------
__global__ __launch_bounds__(256) void cast_f32_bf16(
    const float* __restrict__ in, unsigned short* __restrict__ out, int n) {
  int i = (blockIdx.x * 256 + threadIdx.x) * 4;
  if (i < n) {
    float4 v = *(const float4*)(in + i);
    ushort4 o;
    o.x = f2b(v.x); o.y = f2b(v.y); o.z = f2b(v.z); o.w = f2b(v.w);
    *(ushort4*)(out + i) = o;
  }
}

// ---------- transpose+cast: out_bf16[N][K] = in_f32[K][N], K,N multiples of 64 ----------
__global__ __launch_bounds__(256) void transpose_cast(
    const float* __restrict__ in, unsigned short* __restrict__ out,
    int K, int N) {
  __shared__ __align__(16) unsigned short tile[64][65];
  const int k0 = blockIdx.y * 64, n0 = blockIdx.x * 64;
  const int tid = threadIdx.x;
  const int r = tid >> 4, c4 = tid & 15;
#pragma unroll
  for (int p = 0; p < 4; ++p) {
    int row = p * 16 + r;
    float4 v = *(const float4*)(in + (size_t)(k0 + row) * N + n0 + c4 * 4);
    tile[c4 * 4 + 0][row] = f2b(v.x);
    tile[c4 * 4 + 1][row] = f2b(v.y);
    tile[c4 * 4 + 2][row] = f2b(v.z);
    tile[c4 * 4 + 3][row] = f2b(v.w);
  }
  __syncthreads();
#pragma unroll
  for (int p = 0; p < 4; ++p) {
    int nr = p * 16 + r;
    ushort4 o;
    o.x = tile[nr][c4 * 4 + 0];
    o.y = tile[nr][c4 * 4 + 1];
    o.z = tile[nr][c4 * 4 + 2];
    o.w = tile[nr][c4 * 4 + 3];
    *(ushort4*)(out + (size_t)(n0 + nr) * K + k0 + c4 * 4) = o;
  }
}

// ---------- GEMM v2 (R5-proven): C[M,N] = A[M,K] @ BT[N,K]^T ----------
// 128x128 tile, BK=64, double-buffered LDS (64KB), one barrier per k-step,
// XOR-swizzled staging (pre-swizzled global source, linear LDS dest).
__global__ __launch_bounds__(256) void gemm_bt(
    const unsigned short* __restrict__ A, const unsigned short* __restrict__ BT,
    unsigned short* __restrict__ Cb, float* __restrict__ Cf, int M, int N, int K,
    float cscale) {
  __shared__ __align__(16) unsigned short sA[2][128 * 64];
  __shared__ __align__(16) unsigned short sB[2][128 * 64];
  const int tid = threadIdx.x;
  const int wave = tid >> 6, lane = tid & 63;
  const int quad = lane >> 4, cl = lane & 15;
  const int m0 = blockIdx.y * 128, n0 = blockIdx.x * 128;
  const int wm = (wave >> 1) * 64, wn = (wave & 1) * 64;
  (void)M;

  f32x4 acc[4][4] = {};

  const int lr = lane >> 3;
  const int lc = (lane & 7) ^ lr;
  const unsigned short* gA = A + (size_t)(m0 + wave * 32 + lr) * K + lc * 8;
  const unsigned short* gB = BT + (size_t)(n0 + wave * 32 + lr) * K + lc * 8;
  const int nk = K >> 6;

#pragma unroll
  for (int r = 0; r < 4; ++r) {
    async16(gA + (size_t)r * 8 * K, (char*)sA[0] + (wave * 32 + r * 8) * 128);
    async16(gB + (size_t)r * 8 * K, (char*)sB[0] + (wave * 32 + r * 8) * 128);
  }
  __syncthreads();

  for (int kt = 0; kt < nk; ++kt) {
    const int cur = kt & 1;
    if (kt + 1 < nk) {
      const int k1 = (kt + 1) * 64;
#pragma unroll
      for (int r = 0; r < 4; ++r) {
        async16(gA + (size_t)r * 8 * K + k1,
                (char*)sA[cur ^ 1] + (wave * 32 + r * 8) * 128);
        async16(gB + (size_t)r * 8 * K + k1,
                (char*)sB[cur ^ 1] + (wave * 32 + r * 8) * 128);
      }
    }
    const char* cA = (const char*)sA[cur];
    const char* cB = (const char*)sB[cur];
#pragma unroll
    for (int kk = 0; kk < 2; ++kk) {
      const int g = kk * 4 + quad;
      bf16x8 af[4], bfr[4];
#pragma unroll
      for (int i = 0; i < 4; ++i) {
        int row = wm + i * 16 + cl;
        af[i] = *(const bf16x8*)(cA + row * 128 + (g ^ (cl & 7)) * 16);
      }
#pragma unroll
      for (int j = 0; j < 4; ++j) {
        int row = wn + j * 16 + cl;
        bfr[j] = *(const bf16x8*)(cB + row * 128 + (g ^ (cl & 7)) * 16);
      }
#pragma unroll
      for (int i = 0; i < 4; ++i)
#pragma unroll
        for (int j = 0; j < 4; ++j)
          acc[i][j] = __builtin_amdgcn_mfma_f32_16x16x32_bf16(af[i], bfr[j], acc[i][j], 0, 0, 0);
    }
    __syncthreads();
  }
#pragma unroll
  for (int i = 0; i < 4; ++i)
#pragma unroll
    for (int j = 0; j < 4; ++j)
#pragma unroll
      for (int r = 0; r < 4; ++r) {
        int row = m0 + wm + i * 16 + quad * 4 + r;
        int col = n0 + wn + j * 16 + cl;
        float v = acc[i][j][r];
        if (Cb) Cb[(size_t)row * N + col] = f2b(v * cscale);
        if (Cf) Cf[(size_t)row * N + col] = v;
      }
}

// ---------- fused Q+c projection GEMM (R5 v2 body) ----------
__global__ __launch_bounds__(256) void gemm_qc(
    const unsigned short* __restrict__ A, const unsigned short* __restrict__ BT,
    unsigned short* __restrict__ Qb, unsigned short* __restrict__ cb,
    float* __restrict__ cout, int K, float qscale) {
  __shared__ __align__(16) unsigned short sA[2][128 * 64];
  __shared__ __align__(16) unsigned short sB[2][128 * 64];
  const int tid = threadIdx.x;
  const int wave = tid >> 6, lane = tid & 63;
  const int quad = lane >> 4, cl = lane & 15;
  const int m0 = blockIdx.y * 128, n0 = blockIdx.x * 128;
  const int wm = (wave >> 1) * 64, wn = (wave & 1) * 64;

  f32x4 acc[4][4] = {};

  const int lr = lane >> 3;
  const int lc = (lane & 7) ^ lr;
  const unsigned short* gA = A + (size_t)(m0 + wave * 32 + lr) * K + lc * 8;
  const unsigned short* gB = BT + (size_t)(n0 + wave * 32 + lr) * K + lc * 8;
  const int nk = K >> 6;

#pragma unroll
  for (int r = 0; r < 4; ++r) {
    async16(gA + (size_t)r * 8 * K, (char*)sA[0] + (wave * 32 + r * 8) * 128);
    async16(gB + (size_t)r * 8 * K, (char*)sB[0] + (wave * 32 + r * 8) * 128);
  }
  __syncthreads();

  for (int kt = 0; kt < nk; ++kt) {
    const int cur = kt & 1;
    if (kt + 1 < nk) {
      const int k1 = (kt + 1) * 64;
#pragma unroll
      for (int r = 0; r < 4; ++r) {
        async16(gA + (size_t)r * 8 * K + k1,
                (char*)sA[cur ^ 1] + (wave * 32 + r * 8) * 128);
        async16(gB + (size_t)r * 8 * K + k1,
                (char*)sB[cur ^ 1] + (wave * 32 + r * 8) * 128);
      }
    }
    const char* cA = (const char*)sA[cur];
    const char* cB = (const char*)sB[cur];
#pragma unroll
    for (int kk = 0; kk < 2; ++kk) {
      const int g = kk * 4 + quad;
      bf16x8 af[4], bfr[4];
#pragma unroll
      for (int i = 0; i < 4; ++i) {
        int row = wm + i * 16 + cl;
        af[i] = *(const bf16x8*)(cA + row * 128 + (g ^ (cl & 7)) * 16);
      }
#pragma unroll
      for (int j = 0; j < 4; ++j) {
        int row = wn + j * 16 + cl;
        bfr[j] = *(const bf16x8*)(cB + row * 128 + (g ^ (cl & 7)) * 16);
      }
#pragma unroll
      for (int i = 0; i < 4; ++i)
#pragma unroll
        for (int j = 0; j < 4; ++j)
          acc[i][j] = __builtin_amdgcn_mfma_f32_16x16x32_bf16(af[i], bfr[j], acc[i][j], 0, 0, 0);
    }
    __syncthreads();
  }
  const bool qreg = (n0 < 2048);
#pragma unroll
  for (int i = 0; i < 4; ++i)
#pragma unroll
    for (int j = 0; j < 4; ++j)
#pragma unroll
      for (int r = 0; r < 4; ++r) {
        int row = m0 + wm + i * 16 + quad * 4 + r;
        int col = n0 + wn + j * 16 + cl;
        float v = acc[i][j][r];
        if (qreg) {
          Qb[(size_t)row * 2048 + col] = f2b(v * qscale);
        } else {
          int c2 = col - 2048;
          cb[(size_t)row * 512 + c2] = f2b(v);
          cout[(size_t)row * 512 + c2] = v;
        }
      }
}

// ---------- merged K-proj + V^T-proj (one 1024-block launch) ----------
// f<512 : Kb[4096,2048] = cb[4096,512] @ WkT[2048,512]^T
// f>=512: VT[2048,4096] = WvT[2048,512] @ cb[4096,512]^T
__global__ __launch_bounds__(256) void gemm_kv(
    const unsigned short* __restrict__ cb, const unsigned short* __restrict__ WkT,
    const unsigned short* __restrict__ WvT, unsigned short* __restrict__ Kb,
    unsigned short* __restrict__ VT) {
  __shared__ __align__(16) unsigned short sA[2][128 * 64];
  __shared__ __align__(16) unsigned short sB[2][128 * 64];
  const int tid = threadIdx.x;
  const int wave = tid >> 6, lane = tid & 63;
  const int quad = lane >> 4, cl = lane & 15;
  const int wm = (wave >> 1) * 64, wn = (wave & 1) * 64;
  const int K = 512;

  const unsigned short *A, *BT;
  unsigned short* C;
  int N, m0, n0;
  const int f = blockIdx.x;
  if (f < 512) {
    A = cb; BT = WkT; C = Kb; N = 2048;
    m0 = (f >> 4) * 128; n0 = (f & 15) * 128;
  } else {
    const int g2 = f - 512;
    A = WvT; BT = cb; C = VT; N = 4096;
    m0 = (g2 >> 5) * 128; n0 = (g2 & 31) * 128;
  }

  f32x4 acc[4][4] = {};

  const int lr = lane >> 3;
  const int lc = (lane & 7) ^ lr;
  const unsigned short* gA = A + (size_t)(m0 + wave * 32 + lr) * K + lc * 8;
  const unsigned short* gB = BT + (size_t)(n0 + wave * 32 + lr) * K + lc * 8;
  const int nk = K >> 6;  // 8

#pragma unroll
  for (int r = 0; r < 4; ++r) {
    async16(gA + (size_t)r * 8 * K, (char*)sA[0] + (wave * 32 + r * 8) * 128);
    async16(gB + (size_t)r * 8 * K, (char*)sB[0] + (wave * 32 + r * 8) * 128);
  }
  __syncthreads();

  for (int kt = 0; kt < nk; ++kt) {
    const int cur = kt & 1;
    if (kt + 1 < nk) {
      const int k1 = (kt + 1) * 64;
#pragma unroll
      for (int r = 0; r < 4; ++r) {
        async16(gA + (size_t)r * 8 * K + k1,
                (char*)sA[cur ^ 1] + (wave * 32 + r * 8) * 128);
        async16(gB + (size_t)r * 8 * K + k1,
                (char*)sB[cur ^ 1] + (wave * 32 + r * 8) * 128);
      }
    }
    const char* cA = (const char*)sA[cur];
    const char* cB = (const char*)sB[cur];
#pragma unroll
    for (int kk = 0; kk < 2; ++kk) {
      const int g = kk * 4 + quad;
      bf16x8 af[4], bfr[4];
#pragma unroll
      for (int i = 0; i < 4; ++i) {
        int row = wm + i * 16 + cl;
        af[i] = *(const bf16x8*)(cA + row * 128 + (g ^ (cl & 7)) * 16);
      }
#pragma unroll
      for (int j = 0; j < 4; ++j) {
        int row = wn + j * 16 + cl;
        bfr[j] = *(const bf16x8*)(cB + row * 128 + (g ^ (cl & 7)) * 16);
      }
#pragma unroll
      for (int i = 0; i < 4; ++i)
#pragma unroll
        for (int j = 0; j < 4; ++j)
          acc[i][j] = __builtin_amdgcn_mfma_f32_16x16x32_bf16(af[i], bfr[j], acc[i][j], 0, 0, 0);
    }
    __syncthreads();
  }
#pragma unroll
  for (int i = 0; i < 4; ++i)
#pragma unroll
    for (int j = 0; j < 4; ++j)
#pragma unroll
      for (int r = 0; r < 4; ++r) {
        int row = m0 + wm + i * 16 + quad * 4 + r;
        int col = n0 + wn + j * 16 + cl;
        C[(size_t)row * N + col] = f2b(acc[i][j][r]);
      }
}

// ---------- flash-style causal attention, v6 (R3-exact, 95.4us verified) ----------
// grid (16,16,2), 256 thr, balanced pair {bx, 31-bx} (33 k-tiles/block),
// 56KB LDS -> 2 blocks/CU, sK double-buffered, sVT single + B2, no setprio,
// NO XCD remap: R7/R8 proved the remap cuts FETCH 259->25MB but drops
// occupancy 20->11% (residency loss, mechanism unresolved) and costs
// +40us net. HBM traffic was never the critical path (R3 ran 259MB fully
// covered at 2.9TB/s). Natural blockIdx mapping restored.
__global__ __launch_bounds__(256) void mla_attn(
    const unsigned short* __restrict__ Qm, const unsigned short* __restrict__ Km,
    const unsigned short* __restrict__ Vt, unsigned short* __restrict__ Om, int T) {
  const int ld = 2048;
  const int ldv = 4096;  // B*T
  __shared__ __align__(16) unsigned short sK[2][64 * 128];  // [t][d] xor-swizzled
  __shared__ __align__(16) unsigned short sVT[128 * 64];    // [d][t] xor-swizzled
  __shared__ __align__(16) unsigned short sP[64 * 64];      // [q][t] swz(q)-swizzled
  const int h = blockIdx.y, b = blockIdx.z;
  const int tid = threadIdx.x, wave = tid >> 6, lane = tid & 63;
  const int quad = lane >> 4, cl = lane & 15;
  const int nq = T / 64;  // 32

  for (int phase = 0; phase < 2; ++phase) {
    const int qt = phase ? (nq - 1 - blockIdx.x) : blockIdx.x;

    // Q A-fragments in registers (pre-scaled by 1/sqrt(Dh)*log2e in Q-GEMM)
    bf16x8 qf[4];
    {
      const unsigned short* Qg =
          Qm + (size_t)(b * T + qt * 64 + wave * 16 + cl) * ld + h * 128 + quad * 8;
#pragma unroll
      for (int kk = 0; kk < 4; ++kk)
        qf[kk] = *(const bf16x8*)(Qg + kk * 32);
    }

    float m_i[4], l_part[4];
    f32x4 acc_o[8] = {};
#pragma unroll
    for (int r = 0; r < 4; ++r) { m_i[r] = -1e30f; l_part[r] = 0.f; }

    const unsigned short* Kg0 = Km + (size_t)(b * T) * ld + h * 128;
    const unsigned short* Vg0 = Vt + (size_t)(h * 128) * ldv + (size_t)b * T;

    // prologue: stage K[0] into buffer 0 (prior-phase LDS reads all ended
    // before the prior phase's final B2/B1 barriers).
#pragma unroll
    for (int r = 0; r < 4; ++r) {
      int c0 = r * 256 + wave * 64;
      int c = c0 + lane;
      int row = c >> 4, j = (c & 15) ^ (row & 7);
      async16(Kg0 + (size_t)row * ld + j * 8, (char*)sK[0] + c0 * 16);
    }
    __syncthreads();  // drain K[0] (and phase's Q register loads)

    for (int kt = 0; kt <= qt; ++kt) {
      const int cur = kt & 1;
      const char* cK = (const char*)sK[cur];

      // issue next K tile into the other buffer (overlaps QK^T on sK[cur])
      if (kt < qt) {
        const unsigned short* Kg = Kg0 + (size_t)(kt + 1) * 64 * ld;
        char* dK = (char*)sK[cur ^ 1];
#pragma unroll
        for (int r = 0; r < 4; ++r) {
          int c0 = r * 256 + wave * 64;
          int c = c0 + lane;
          int row = c >> 4, j = (c & 15) ^ (row & 7);
          async16(Kg + (size_t)row * ld + j * 8, dK + c0 * 16);
        }
      }
      // issue this tile's V (prev PV reads of sVT completed at B2)
      {
        const unsigned short* Vg = Vg0 + kt * 64;
#pragma unroll
        for (int r = 0; r < 4; ++r) {
          int c0 = r * 256 + wave * 64;
          int c = c0 + lane;
          int d = c >> 3, jv = (c & 7) ^ (d & 7);
          async16(Vg + (size_t)d * ldv + jv * 8, (char*)sVT + c0 * 16);
        }
      }

      // S = Q @ K^T : 16 q-rows (this wave) x 64 keys (exp2 domain, pre-scaled)
      f32x4 s[4] = {};
#pragma unroll
      for (int kk = 0; kk < 4; ++kk) {
#pragma unroll
        for (int j = 0; j < 4; ++j) {
          int t = j * 16 + cl;
          int jp = (kk * 4 + quad) ^ (t & 7);
          bf16x8 bk = *(const bf16x8*)(cK + (t * 16 + jp) * 16);
          s[j] = __builtin_amdgcn_mfma_f32_16x16x32_bf16(qf[kk], bk, s[j], 0, 0, 0);
        }
      }

      // causal mask + online softmax (deferred max, lane-local fast path)
      const bool need_mask = (kt == qt);
#pragma unroll
      for (int r = 0; r < 4; ++r) {
        int q_l = wave * 16 + quad * 4 + r;
        float mxl = -1e30f;
#pragma unroll
        for (int j = 0; j < 4; ++j) {
          float v = s[j][r];
          if (need_mask) {
            int t_l = j * 16 + cl;
            if (t_l > q_l) v = -1e30f;
            s[j][r] = v;
          }
          mxl = fmaxf(mxl, v);
        }
        if (__any(mxl > m_i[r] + 6.f)) {
          float mx = mxl;
#pragma unroll
          for (int off = 1; off < 16; off <<= 1)
            mx = fmaxf(mx, __shfl_xor(mx, off));
          float m_new = fmaxf(m_i[r], mx);
          float alpha = exp2f(m_i[r] - m_new);
          m_i[r] = m_new;
          l_part[r] *= alpha;
#pragma unroll
          for (int jd = 0; jd < 8; ++jd)
            acc_o[jd][r] *= alpha;
        }
        float rs = 0.f;
#pragma unroll
        for (int j = 0; j < 4; ++j) {
          float p = exp2f(s[j][r] - m_i[r]);
          s[j][r] = p;
          rs += p;
        }
        l_part[r] += rs;  // per-lane partial; cross-lane reduce in epilogue
      }

      // write P swizzled into sP (wave-local rows -> no barrier needed)
#pragma unroll
      for (int j = 0; j < 4; ++j)
#pragma unroll
        for (int r = 0; r < 4; ++r) {
          int q = wave * 16 + quad * 4 + r;
          int swz = (q & 7) ^ (((q >> 3) & 1) << 1);
          int t = j * 16 + cl;
          int jp = (t >> 3) ^ swz;
          sP[(q * 8 + jp) * 8 + (t & 7)] = f2b(s[j][r]);
        }

      __syncthreads();  // B1: drains K[kt+1]+V[kt] (covered); sK[cur] reads done

      // O += P @ V (A from own-wave sP rows, B from sVT; both b128)
#pragma unroll
      for (int kk2 = 0; kk2 < 2; ++kk2) {
        int q = wave * 16 + cl;
        int swz = (q & 7) ^ (((q >> 3) & 1) << 1);
        int jp = (kk2 * 4 + quad) ^ swz;
        bf16x8 ap = *(const bf16x8*)((const char*)sP + (q * 8 + jp) * 16);
#pragma unroll
        for (int jd = 0; jd < 8; ++jd) {
          int d = jd * 16 + cl;
          int jpv = (kk2 * 4 + quad) ^ (d & 7);
          bf16x8 bv = *(const bf16x8*)((const char*)sVT + (d * 8 + jpv) * 16);
          acc_o[jd] = __builtin_amdgcn_mfma_f32_16x16x32_bf16(ap, bv, acc_o[jd], 0, 0, 0);
        }
      }

      __syncthreads();  // B2: pure sync — sVT reads done before next V issue
    }

    // epilogue: reduce l partials across the 16 row lanes, normalize, store
#pragma unroll
    for (int r = 0; r < 4; ++r) {
      float l = l_part[r];
#pragma unroll
      for (int off = 1; off < 16; off <<= 1)
        l += __shfl_xor(l, off);
      float inv = 1.f / l;
      int row = b * T + qt * 64 + wave * 16 + quad * 4 + r;
#pragma unroll
      for (int jd = 0; jd < 8; ++jd)
        Om[(size_t)row * ld + h * 128 + jd * 16 + cl] = f2b(acc_o[jd][r] * inv);
    }
  }
}

// ---------- launch ----------
extern "C" void kernel_launch(void* const* d_in, const int* in_sizes, int n_in,
                              void* d_out, int out_size, void* d_ws, size_t ws_size,
                              hipStream_t stream) {
  (void)in_sizes; (void)n_in; (void)out_size; (void)ws_size;
  const int B = 2, T = 2048, Dm = 2048, H = 16, Dh = 128, R = 512;
  const int M = B * T;  // 4096
  const float* x     = (const float*)d_in[0];
  const float* Wq    = (const float*)d_in[1];
  const float* Wdown = (const float*)d_in[2];
  const float* Wkup  = (const float*)d_in[3];
  const float* Wvup  = (const float*)d_in[4];
  const float* Wo    = (const float*)d_in[5];

  float* out  = (float*)d_out;                      // (B*T) x 2048 fp32
  float* cout = out + (size_t)M * Dm;               // (B*T) x 512  fp32

  unsigned short* ws  = (unsigned short*)d_ws;      // bf16 scratch
  unsigned short* WqT = ws;                         // 2048x2048 (stacked B rows 0..2047)
  unsigned short* WdT = WqT + (size_t)Dm * Dm;      // 512x2048  (stacked B rows 2048..2559)
  unsigned short* WoT = WdT + (size_t)R * Dm;       // 2048x2048
  unsigned short* WkT = WoT + (size_t)Dm * Dm;      // 2048x512
  unsigned short* WvT = WkT + (size_t)Dm * R;       // 2048x512
  unsigned short* xb  = WvT + (size_t)Dm * R;       // 4096x2048 (reused as AO)
  unsigned short* cb  = xb + (size_t)M * Dm;        // 4096x512
  unsigned short* Qb  = cb + (size_t)M * R;         // 4096x2048
  unsigned short* Kb  = Qb + (size_t)M * Dm;        // 4096x2048
  unsigned short* VT  = Kb + (size_t)M * Dm;        // 2048x4096 (V^T, d-major)
  unsigned short* AO  = xb;                         // alias: xb dead after Q-proj

  // softmax scale folded into Q: 1/sqrt(128) * log2(e)
  const float qscale = 0.08838834764831845f * 1.4426950408889634f;

  // input casts / weight transposes -> bf16 BT form
  cast_f32_bf16<<<(M * Dm) / 1024, 256, 0, stream>>>(x, xb, M * Dm);
  transpose_cast<<<dim3(32, 32), 256, 0, stream>>>(Wq, WqT, Dm, Dm);
  transpose_cast<<<dim3(8, 32), 256, 0, stream>>>(Wdown, WdT, Dm, R);
  transpose_cast<<<dim3(32, 32), 256, 0, stream>>>(Wo, WoT, Dm, Dm);
  transpose_cast<<<dim3(32, 8), 256, 0, stream>>>(Wkup, WkT, R, Dm);
  transpose_cast<<<dim3(32, 8), 256, 0, stream>>>(Wvup, WvT, R, Dm);

  // fused Q + c projection: grid (2560/128, 4096/128) = (20,32) = 640 blocks
  gemm_qc<<<dim3(20, 32), 256, 0, stream>>>(xb, WqT, Qb, cb, cout, Dm, qscale);

  // merged K-proj + V^T-proj: 1024 blocks
  gemm_kv<<<1024, 256, 0, stream>>>(cb, WkT, WvT, Kb, VT);

  // causal attention: balanced pair per block (natural blockIdx mapping)
  mla_attn<<<dim3(T / 128, H, B), 256, 0, stream>>>(Qb, Kb, VT, AO, T);

  // output projection (fp32 out)
  gemm_bt<<<dim3(Dm / 128, M / 128), 256, 0, stream>>>(AO, WoT, nullptr, out, M, Dm, Dm, 1.f);
  (void)Dh; (void)H;
}

// Round 10
// 349.856 us; speedup vs baseline: 1.1811x; 1.0246x over previous
//
#include <hip/hip_runtime.h>

// ---------- common helpers ----------
typedef short bf16x8 __attribute__((ext_vector_type(8)));
typedef float f32x4 __attribute__((ext_vector_type(4)));

__device__ __forceinline__ void async16(const void* g, const void* l) {
  __builtin_amdgcn_global_load_lds(
      (const __attribute__((address_space(1))) unsigned int*)g,
      (__attribute__((address_space(3))) unsigned int*)(void*)(uintptr_t)l,
      16, 0, 0);
}

__device__ __forceinline__ unsigned short f2b(float f) {
  unsigned int u = __float_as_uint(f);
  u += 0x7fffu + ((u >> 16) & 1u);   // round-to-nearest-even
  return (unsigned short)(u >> 16);
}

// ---------- fused prep: cast x + all 5 weight transposes, ONE launch ----------
// R9 ran 6 serialized launches (cast 8192 blocks + 5 transposes of 256-1024
// blocks each): 5 kernel-boundary drains on tiny grids. Flat block-id ranges
// (gemm_kv's proven trick); per-tile math byte-identical to the old kernels.
//   f in [0, 8192)            : cast chunk f (1024 floats)
//   [8192, 9216)              : Wq    [2048][2048] -> WqT   (bx=l&31, by=l>>5)
//   [9216, 9472)              : Wdown [2048][512]  -> WdT   (bx=l&7,  by=l>>3)
//   [9472, 10496)             : Wo    [2048][2048] -> WoT   (bx=l&31, by=l>>5)
//   [10496, 10752)            : Wkup  [512][2048]  -> WkT   (bx=l&31, by=l>>5)
//   [10752, 11008)            : Wvup  [512][2048]  -> WvT   (bx=l&31, by=l>>5)
__device__ __forceinline__ void transpose_tile(
    const float* __restrict__ in, unsigned short* __restrict__ out,
    int K, int N, int bx, int by, unsigned short (*tile)[65]) {
  const int k0 = by * 64, n0 = bx * 64;
  const int tid = threadIdx.x;
  const int r = tid >> 4, c4 = tid & 15;
#pragma unroll
  for (int p = 0; p < 4; ++p) {
    int row = p * 16 + r;
    float4 v = *(const float4*)(in + (size_t)(k0 + row) * N + n0 + c4 * 4);
    tile[c4 * 4 + 0][row] = f2b(v.x);
    tile[c4 * 4 + 1][row] = f2b(v.y);
    tile[c4 * 4 + 2][row] = f2b(v.z);
    tile[c4 * 4 + 3][row] = f2b(v.w);
  }
  __syncthreads();
#pragma unroll
  for (int p = 0; p < 4; ++p) {
    int nr = p * 16 + r;
    ushort4 o;
    o.x = tile[nr][c4 * 4 + 0];
    o.y = tile[nr][c4 * 4 + 1];
    o.z = tile[nr][c4 * 4 + 2];
    o.w = tile[nr][c4 * 4 + 3];
    *(ushort4*)(out + (size_t)(n0 + nr) * K + k0 + c4 * 4) = o;
  }
}

__global__ __launch_bounds__(256) void prep_all(
    const float* __restrict__ x, unsigned short* __restrict__ xb, int ncast,
    const float* __restrict__ Wq, unsigned short* __restrict__ WqT,
    const float* __restrict__ Wdown, unsigned short* __restrict__ WdT,
    const float* __restrict__ Wo, unsigned short* __restrict__ WoT,
    const float* __restrict__ Wkup, unsigned short* __restrict__ WkT,
    const float* __restrict__ Wvup, unsigned short* __restrict__ WvT) {
  __shared__ __align__(16) unsigned short tile[64][65];
  const int f = blockIdx.x;
  if (f < 8192) {
    int i = (f * 256 + threadIdx.x) * 4;
    if (i < ncast) {
      float4 v = *(const float4*)(x + i);
      ushort4 o;
      o.x = f2b(v.x); o.y = f2b(v.y); o.z = f2b(v.z); o.w = f2b(v.w);
      *(ushort4*)(xb + i) = o;
    }
  } else if (f < 9216) {
    int l = f - 8192;
    transpose_tile(Wq, WqT, 2048, 2048, l & 31, l >> 5, tile);
  } else if (f < 9472) {
    int l = f - 9216;
    transpose_tile(Wdown, WdT, 2048, 512, l & 7, l >> 3, tile);
  } else if (f < 10496) {
    int l = f - 9472;
    transpose_tile(Wo, WoT, 2048, 2048, l & 31, l >> 5, tile);
  } else if (f < 10752) {
    int l = f - 10496;
    transpose_tile(Wkup, WkT, 512, 2048, l & 31, l >> 5, tile);
  } else {
    int l = f - 10752;
    transpose_tile(Wvup, WvT, 512, 2048, l & 31, l >> 5, tile);
  }
}

// ---------- GEMM v2 (R5-proven): C[M,N] = A[M,K] @ BT[N,K]^T ----------
// 128x128 tile, BK=64, double-buffered LDS (64KB), one barrier per k-step,
// XOR-swizzled staging (pre-swizzled global source, linear LDS dest).
__global__ __launch_bounds__(256) void gemm_bt(
    const unsigned short* __restrict__ A, const unsigned short* __restrict__ BT,
    unsigned short* __restrict__ Cb, float* __restrict__ Cf, int M, int N, int K,
    float cscale) {
  __shared__ __align__(16) unsigned short sA[2][128 * 64];
  __shared__ __align__(16) unsigned short sB[2][128 * 64];
  const int tid = threadIdx.x;
  const int wave = tid >> 6, lane = tid & 63;
  const int quad = lane >> 4, cl = lane & 15;
  const int m0 = blockIdx.y * 128, n0 = blockIdx.x * 128;
  const int wm = (wave >> 1) * 64, wn = (wave & 1) * 64;
  (void)M;

  f32x4 acc[4][4] = {};

  const int lr = lane >> 3;
  const int lc = (lane & 7) ^ lr;
  const unsigned short* gA = A + (size_t)(m0 + wave * 32 + lr) * K + lc * 8;
  const unsigned short* gB = BT + (size_t)(n0 + wave * 32 + lr) * K + lc * 8;
  const int nk = K >> 6;

#pragma unroll
  for (int r = 0; r < 4; ++r) {
    async16(gA + (size_t)r * 8 * K, (char*)sA[0] + (wave * 32 + r * 8) * 128);
    async16(gB + (size_t)r * 8 * K, (char*)sB[0] + (wave * 32 + r * 8) * 128);
  }
  __syncthreads();

  for (int kt = 0; kt < nk; ++kt) {
    const int cur = kt & 1;
    if (kt + 1 < nk) {
      const int k1 = (kt + 1) * 64;
#pragma unroll
      for (int r = 0; r < 4; ++r) {
        async16(gA + (size_t)r * 8 * K + k1,
                (char*)sA[cur ^ 1] + (wave * 32 + r * 8) * 128);
        async16(gB + (size_t)r * 8 * K + k1,
                (char*)sB[cur ^ 1] + (wave * 32 + r * 8) * 128);
      }
    }
    const char* cA = (const char*)sA[cur];
    const char* cB = (const char*)sB[cur];
#pragma unroll
    for (int kk = 0; kk < 2; ++kk) {
      const int g = kk * 4 + quad;
      bf16x8 af[4], bfr[4];
#pragma unroll
      for (int i = 0; i < 4; ++i) {
        int row = wm + i * 16 + cl;
        af[i] = *(const bf16x8*)(cA + row * 128 + (g ^ (cl & 7)) * 16);
      }
#pragma unroll
      for (int j = 0; j < 4; ++j) {
        int row = wn + j * 16 + cl;
        bfr[j] = *(const bf16x8*)(cB + row * 128 + (g ^ (cl & 7)) * 16);
      }
#pragma unroll
      for (int i = 0; i < 4; ++i)
#pragma unroll
        for (int j = 0; j < 4; ++j)
          acc[i][j] = __builtin_amdgcn_mfma_f32_16x16x32_bf16(af[i], bfr[j], acc[i][j], 0, 0, 0);
    }
    __syncthreads();
  }
#pragma unroll
  for (int i = 0; i < 4; ++i)
#pragma unroll
    for (int j = 0; j < 4; ++j)
#pragma unroll
      for (int r = 0; r < 4; ++r) {
        int row = m0 + wm + i * 16 + quad * 4 + r;
        int col = n0 + wn + j * 16 + cl;
        float v = acc[i][j][r];
        if (Cb) Cb[(size_t)row * N + col] = f2b(v * cscale);
        if (Cf) Cf[(size_t)row * N + col] = v;
      }
}

// ---------- fused Q+c projection GEMM (R5 v2 body) ----------
__global__ __launch_bounds__(256) void gemm_qc(
    const unsigned short* __restrict__ A, const unsigned short* __restrict__ BT,
    unsigned short* __restrict__ Qb, unsigned short* __restrict__ cb,
    float* __restrict__ cout, int K, float qscale) {
  __shared__ __align__(16) unsigned short sA[2][128 * 64];
  __shared__ __align__(16) unsigned short sB[2][128 * 64];
  const int tid = threadIdx.x;
  const int wave = tid >> 6, lane = tid & 63;
  const int quad = lane >> 4, cl = lane & 15;
  const int m0 = blockIdx.y * 128, n0 = blockIdx.x * 128;
  const int wm = (wave >> 1) * 64, wn = (wave & 1) * 64;

  f32x4 acc[4][4] = {};

  const int lr = lane >> 3;
  const int lc = (lane & 7) ^ lr;
  const unsigned short* gA = A + (size_t)(m0 + wave * 32 + lr) * K + lc * 8;
  const unsigned short* gB = BT + (size_t)(n0 + wave * 32 + lr) * K + lc * 8;
  const int nk = K >> 6;

#pragma unroll
  for (int r = 0; r < 4; ++r) {
    async16(gA + (size_t)r * 8 * K, (char*)sA[0] + (wave * 32 + r * 8) * 128);
    async16(gB + (size_t)r * 8 * K, (char*)sB[0] + (wave * 32 + r * 8) * 128);
  }
  __syncthreads();

  for (int kt = 0; kt < nk; ++kt) {
    const int cur = kt & 1;
    if (kt + 1 < nk) {
      const int k1 = (kt + 1) * 64;
#pragma unroll
      for (int r = 0; r < 4; ++r) {
        async16(gA + (size_t)r * 8 * K + k1,
                (char*)sA[cur ^ 1] + (wave * 32 + r * 8) * 128);
        async16(gB + (size_t)r * 8 * K + k1,
                (char*)sB[cur ^ 1] + (wave * 32 + r * 8) * 128);
      }
    }
    const char* cA = (const char*)sA[cur];
    const char* cB = (const char*)sB[cur];
#pragma unroll
    for (int kk = 0; kk < 2; ++kk) {
      const int g = kk * 4 + quad;
      bf16x8 af[4], bfr[4];
#pragma unroll
      for (int i = 0; i < 4; ++i) {
        int row = wm + i * 16 + cl;
        af[i] = *(const bf16x8*)(cA + row * 128 + (g ^ (cl & 7)) * 16);
      }
#pragma unroll
      for (int j = 0; j < 4; ++j) {
        int row = wn + j * 16 + cl;
        bfr[j] = *(const bf16x8*)(cB + row * 128 + (g ^ (cl & 7)) * 16);
      }
#pragma unroll
      for (int i = 0; i < 4; ++i)
#pragma unroll
        for (int j = 0; j < 4; ++j)
          acc[i][j] = __builtin_amdgcn_mfma_f32_16x16x32_bf16(af[i], bfr[j], acc[i][j], 0, 0, 0);
    }
    __syncthreads();
  }
  const bool qreg = (n0 < 2048);
#pragma unroll
  for (int i = 0; i < 4; ++i)
#pragma unroll
    for (int j = 0; j < 4; ++j)
#pragma unroll
      for (int r = 0; r < 4; ++r) {
        int row = m0 + wm + i * 16 + quad * 4 + r;
        int col = n0 + wn + j * 16 + cl;
        float v = acc[i][j][r];
        if (qreg) {
          Qb[(size_t)row * 2048 + col] = f2b(v * qscale);
        } else {
          int c2 = col - 2048;
          cb[(size_t)row * 512 + c2] = f2b(v);
          cout[(size_t)row * 512 + c2] = v;
        }
      }
}

// ---------- merged K-proj + V^T-proj (one 1024-block launch) ----------
// f<512 : Kb[4096,2048] = cb[4096,512] @ WkT[2048,512]^T
// f>=512: VT[2048,4096] = WvT[2048,512] @ cb[4096,512]^T
__global__ __launch_bounds__(256) void gemm_kv(
    const unsigned short* __restrict__ cb, const unsigned short* __restrict__ WkT,
    const unsigned short* __restrict__ WvT, unsigned short* __restrict__ Kb,
    unsigned short* __restrict__ VT) {
  __shared__ __align__(16) unsigned short sA[2][128 * 64];
  __shared__ __align__(16) unsigned short sB[2][128 * 64];
  const int tid = threadIdx.x;
  const int wave = tid >> 6, lane = tid & 63;
  const int quad = lane >> 4, cl = lane & 15;
  const int wm = (wave >> 1) * 64, wn = (wave & 1) * 64;
  const int K = 512;

  const unsigned short *A, *BT;
  unsigned short* C;
  int N, m0, n0;
  const int f = blockIdx.x;
  if (f < 512) {
    A = cb; BT = WkT; C = Kb; N = 2048;
    m0 = (f >> 4) * 128; n0 = (f & 15) * 128;
  } else {
    const int g2 = f - 512;
    A = WvT; BT = cb; C = VT; N = 4096;
    m0 = (g2 >> 5) * 128; n0 = (g2 & 31) * 128;
  }

  f32x4 acc[4][4] = {};

  const int lr = lane >> 3;
  const int lc = (lane & 7) ^ lr;
  const unsigned short* gA = A + (size_t)(m0 + wave * 32 + lr) * K + lc * 8;
  const unsigned short* gB = BT + (size_t)(n0 + wave * 32 + lr) * K + lc * 8;
  const int nk = K >> 6;  // 8

#pragma unroll
  for (int r = 0; r < 4; ++r) {
    async16(gA + (size_t)r * 8 * K, (char*)sA[0] + (wave * 32 + r * 8) * 128);
    async16(gB + (size_t)r * 8 * K, (char*)sB[0] + (wave * 32 + r * 8) * 128);
  }
  __syncthreads();

  for (int kt = 0; kt < nk; ++kt) {
    const int cur = kt & 1;
    if (kt + 1 < nk) {
      const int k1 = (kt + 1) * 64;
#pragma unroll
      for (int r = 0; r < 4; ++r) {
        async16(gA + (size_t)r * 8 * K + k1,
                (char*)sA[cur ^ 1] + (wave * 32 + r * 8) * 128);
        async16(gB + (size_t)r * 8 * K + k1,
                (char*)sB[cur ^ 1] + (wave * 32 + r * 8) * 128);
      }
    }
    const char* cA = (const char*)sA[cur];
    const char* cB = (const char*)sB[cur];
#pragma unroll
    for (int kk = 0; kk < 2; ++kk) {
      const int g = kk * 4 + quad;
      bf16x8 af[4], bfr[4];
#pragma unroll
      for (int i = 0; i < 4; ++i) {
        int row = wm + i * 16 + cl;
        af[i] = *(const bf16x8*)(cA + row * 128 + (g ^ (cl & 7)) * 16);
      }
#pragma unroll
      for (int j = 0; j < 4; ++j) {
        int row = wn + j * 16 + cl;
        bfr[j] = *(const bf16x8*)(cB + row * 128 + (g ^ (cl & 7)) * 16);
      }
#pragma unroll
      for (int i = 0; i < 4; ++i)
#pragma unroll
        for (int j = 0; j < 4; ++j)
          acc[i][j] = __builtin_amdgcn_mfma_f32_16x16x32_bf16(af[i], bfr[j], acc[i][j], 0, 0, 0);
    }
    __syncthreads();
  }
#pragma unroll
  for (int i = 0; i < 4; ++i)
#pragma unroll
    for (int j = 0; j < 4; ++j)
#pragma unroll
      for (int r = 0; r < 4; ++r) {
        int row = m0 + wm + i * 16 + quad * 4 + r;
        int col = n0 + wn + j * 16 + cl;
        C[(size_t)row * N + col] = f2b(acc[i][j][r]);
      }
}

// ---------- flash-style causal attention, v6 (R3/R9-exact, 94.5us verified) ----------
// grid (16,16,2), 256 thr, balanced pair {bx, 31-bx} (33 k-tiles/block),
// 56KB LDS -> 2 blocks/CU, sK double-buffered, sVT single + B2, no setprio,
// no XCD remap (R7/R8: remap cut FETCH 10x but halved residency, +40us net).
__global__ __launch_bounds__(256) void mla_attn(
    const unsigned short* __restrict__ Qm, const unsigned short* __restrict__ Km,
    const unsigned short* __restrict__ Vt, unsigned short* __restrict__ Om, int T) {
  const int ld = 2048;
  const int ldv = 4096;  // B*T
  __shared__ __align__(16) unsigned short sK[2][64 * 128];  // [t][d] xor-swizzled
  __shared__ __align__(16) unsigned short sVT[128 * 64];    // [d][t] xor-swizzled
  __shared__ __align__(16) unsigned short sP[64 * 64];      // [q][t] swz(q)-swizzled
  const int h = blockIdx.y, b = blockIdx.z;
  const int tid = threadIdx.x, wave = tid >> 6, lane = tid & 63;
  const int quad = lane >> 4, cl = lane & 15;
  const int nq = T / 64;  // 32

  for (int phase = 0; phase < 2; ++phase) {
    const int qt = phase ? (nq - 1 - blockIdx.x) : blockIdx.x;

    // Q A-fragments in registers (pre-scaled by 1/sqrt(Dh)*log2e in Q-GEMM)
    bf16x8 qf[4];
    {
      const unsigned short* Qg =
          Qm + (size_t)(b * T + qt * 64 + wave * 16 + cl) * ld + h * 128 + quad * 8;
#pragma unroll
      for (int kk = 0; kk < 4; ++kk)
        qf[kk] = *(const bf16x8*)(Qg + kk * 32);
    }

    float m_i[4], l_part[4];
    f32x4 acc_o[8] = {};
#pragma unroll
    for (int r = 0; r < 4; ++r) { m_i[r] = -1e30f; l_part[r] = 0.f; }

    const unsigned short* Kg0 = Km + (size_t)(b * T) * ld + h * 128;
    const unsigned short* Vg0 = Vt + (size_t)(h * 128) * ldv + (size_t)b * T;

    // prologue: stage K[0] into buffer 0 (prior-phase LDS reads all ended
    // before the prior phase's final B2/B1 barriers).
#pragma unroll
    for (int r = 0; r < 4; ++r) {
      int c0 = r * 256 + wave * 64;
      int c = c0 + lane;
      int row = c >> 4, j = (c & 15) ^ (row & 7);
      async16(Kg0 + (size_t)row * ld + j * 8, (char*)sK[0] + c0 * 16);
    }
    __syncthreads();  // drain K[0] (and phase's Q register loads)

    for (int kt = 0; kt <= qt; ++kt) {
      const int cur = kt & 1;
      const char* cK = (const char*)sK[cur];

      // issue next K tile into the other buffer (overlaps QK^T on sK[cur])
      if (kt < qt) {
        const unsigned short* Kg = Kg0 + (size_t)(kt + 1) * 64 * ld;
        char* dK = (char*)sK[cur ^ 1];
#pragma unroll
        for (int r = 0; r < 4; ++r) {
          int c0 = r * 256 + wave * 64;
          int c = c0 + lane;
          int row = c >> 4, j = (c & 15) ^ (row & 7);
          async16(Kg + (size_t)row * ld + j * 8, dK + c0 * 16);
        }
      }
      // issue this tile's V (prev PV reads of sVT completed at B2)
      {
        const unsigned short* Vg = Vg0 + kt * 64;
#pragma unroll
        for (int r = 0; r < 4; ++r) {
          int c0 = r * 256 + wave * 64;
          int c = c0 + lane;
          int d = c >> 3, jv = (c & 7) ^ (d & 7);
          async16(Vg + (size_t)d * ldv + jv * 8, (char*)sVT + c0 * 16);
        }
      }

      // S = Q @ K^T : 16 q-rows (this wave) x 64 keys (exp2 domain, pre-scaled)
      f32x4 s[4] = {};
#pragma unroll
      for (int kk = 0; kk < 4; ++kk) {
#pragma unroll
        for (int j = 0; j < 4; ++j) {
          int t = j * 16 + cl;
          int jp = (kk * 4 + quad) ^ (t & 7);
          bf16x8 bk = *(const bf16x8*)(cK + (t * 16 + jp) * 16);
          s[j] = __builtin_amdgcn_mfma_f32_16x16x32_bf16(qf[kk], bk, s[j], 0, 0, 0);
        }
      }

      // causal mask + online softmax (deferred max, lane-local fast path)
      const bool need_mask = (kt == qt);
#pragma unroll
      for (int r = 0; r < 4; ++r) {
        int q_l = wave * 16 + quad * 4 + r;
        float mxl = -1e30f;
#pragma unroll
        for (int j = 0; j < 4; ++j) {
          float v = s[j][r];
          if (need_mask) {
            int t_l = j * 16 + cl;
            if (t_l > q_l) v = -1e30f;
            s[j][r] = v;
          }
          mxl = fmaxf(mxl, v);
        }
        if (__any(mxl > m_i[r] + 6.f)) {
          float mx = mxl;
#pragma unroll
          for (int off = 1; off < 16; off <<= 1)
            mx = fmaxf(mx, __shfl_xor(mx, off));
          float m_new = fmaxf(m_i[r], mx);
          float alpha = exp2f(m_i[r] - m_new);
          m_i[r] = m_new;
          l_part[r] *= alpha;
#pragma unroll
          for (int jd = 0; jd < 8; ++jd)
            acc_o[jd][r] *= alpha;
        }
        float rs = 0.f;
#pragma unroll
        for (int j = 0; j < 4; ++j) {
          float p = exp2f(s[j][r] - m_i[r]);
          s[j][r] = p;
          rs += p;
        }
        l_part[r] += rs;  // per-lane partial; cross-lane reduce in epilogue
      }

      // write P swizzled into sP (wave-local rows -> no barrier needed)
#pragma unroll
      for (int j = 0; j < 4; ++j)
#pragma unroll
        for (int r = 0; r < 4; ++r) {
          int q = wave * 16 + quad * 4 + r;
          int swz = (q & 7) ^ (((q >> 3) & 1) << 1);
          int t = j * 16 + cl;
          int jp = (t >> 3) ^ swz;
          sP[(q * 8 + jp) * 8 + (t & 7)] = f2b(s[j][r]);
        }

      __syncthreads();  // B1: drains K[kt+1]+V[kt] (covered); sK[cur] reads done

      // O += P @ V (A from own-wave sP rows, B from sVT; both b128)
#pragma unroll
      for (int kk2 = 0; kk2 < 2; ++kk2) {
        int q = wave * 16 + cl;
        int swz = (q & 7) ^ (((q >> 3) & 1) << 1);
        int jp = (kk2 * 4 + quad) ^ swz;
        bf16x8 ap = *(const bf16x8*)((const char*)sP + (q * 8 + jp) * 16);
#pragma unroll
        for (int jd = 0; jd < 8; ++jd) {
          int d = jd * 16 + cl;
          int jpv = (kk2 * 4 + quad) ^ (d & 7);
          bf16x8 bv = *(const bf16x8*)((const char*)sVT + (d * 8 + jpv) * 16);
          acc_o[jd] = __builtin_amdgcn_mfma_f32_16x16x32_bf16(ap, bv, acc_o[jd], 0, 0, 0);
        }
      }

      __syncthreads();  // B2: pure sync — sVT reads done before next V issue
    }

    // epilogue: reduce l partials across the 16 row lanes, normalize, store
#pragma unroll
    for (int r = 0; r < 4; ++r) {
      float l = l_part[r];
#pragma unroll
      for (int off = 1; off < 16; off <<= 1)
        l += __shfl_xor(l, off);
      float inv = 1.f / l;
      int row = b * T + qt * 64 + wave * 16 + quad * 4 + r;
#pragma unroll
      for (int jd = 0; jd < 8; ++jd)
        Om[(size_t)row * ld + h * 128 + jd * 16 + cl] = f2b(acc_o[jd][r] * inv);
    }
  }
}

// ---------- launch ----------
extern "C" void kernel_launch(void* const* d_in, const int* in_sizes, int n_in,
                              void* d_out, int out_size, void* d_ws, size_t ws_size,
                              hipStream_t stream) {
  (void)in_sizes; (void)n_in; (void)out_size; (void)ws_size;
  const int B = 2, T = 2048, Dm = 2048, H = 16, Dh = 128, R = 512;
  const int M = B * T;  // 4096
  const float* x     = (const float*)d_in[0];
  const float* Wq    = (const float*)d_in[1];
  const float* Wdown = (const float*)d_in[2];
  const float* Wkup  = (const float*)d_in[3];
  const float* Wvup  = (const float*)d_in[4];
  const float* Wo    = (const float*)d_in[5];

  float* out  = (float*)d_out;                      // (B*T) x 2048 fp32
  float* cout = out + (size_t)M * Dm;               // (B*T) x 512  fp32

  unsigned short* ws  = (unsigned short*)d_ws;      // bf16 scratch
  unsigned short* WqT = ws;                         // 2048x2048 (stacked B rows 0..2047)
  unsigned short* WdT = WqT + (size_t)Dm * Dm;      // 512x2048  (stacked B rows 2048..2559)
  unsigned short* WoT = WdT + (size_t)R * Dm;       // 2048x2048
  unsigned short* WkT = WoT + (size_t)Dm * Dm;      // 2048x512
  unsigned short* WvT = WkT + (size_t)Dm * R;       // 2048x512
  unsigned short* xb  = WvT + (size_t)Dm * R;       // 4096x2048 (reused as AO)
  unsigned short* cb  = xb + (size_t)M * Dm;        // 4096x512
  unsigned short* Qb  = cb + (size_t)M * R;         // 4096x2048
  unsigned short* Kb  = Qb + (size_t)M * Dm;        // 4096x2048
  unsigned short* VT  = Kb + (size_t)M * Dm;        // 2048x4096 (V^T, d-major)
  unsigned short* AO  = xb;                         // alias: xb dead after Q-proj

  // softmax scale folded into Q: 1/sqrt(128) * log2(e)
  const float qscale = 0.08838834764831845f * 1.4426950408889634f;

  // fused prep: cast + all 5 weight transposes in ONE launch (11008 blocks)
  prep_all<<<11008, 256, 0, stream>>>(x, xb, M * Dm,
                                      Wq, WqT, Wdown, WdT, Wo, WoT,
                                      Wkup, WkT, Wvup, WvT);

  // fused Q + c projection: grid (2560/128, 4096/128) = (20,32) = 640 blocks
  gemm_qc<<<dim3(20, 32), 256, 0, stream>>>(xb, WqT, Qb, cb, cout, Dm, qscale);

  // merged K-proj + V^T-proj: 1024 blocks
  gemm_kv<<<1024, 256, 0, stream>>>(cb, WkT, WvT, Kb, VT);

  // causal attention: balanced pair per block (natural blockIdx mapping)
  mla_attn<<<dim3(T / 128, H, B), 256, 0, stream>>>(Qb, Kb, VT, AO, T);

  // output projection (fp32 out)
  gemm_bt<<<dim3(Dm / 128, M / 128), 256, 0, stream>>>(AO, WoT, nullptr, out, M, Dm, Dm, 1.f);
  (void)Dh; (void)H;
}